// Round 4
// baseline (1220.269 us; speedup 1.0000x reference)
//
#include <hip/hip_runtime.h>
#include <cfloat>
#include <cmath>

constexpr int NB = 8;
constexpr int NP = 2048;
constexpr float LOG2E_F = 1.4426950408889634f;

typedef __attribute__((ext_vector_type(4))) float f32x4;
typedef __attribute__((ext_vector_type(8))) short bf16x8;
#define MFMA16(a, b, c) __builtin_amdgcn_mfma_f32_16x16x32_bf16(a, b, c, 0, 0, 0)

__device__ inline ushort f2bf(float f) {   // round-to-nearest-even f32 -> bf16
  union { float f; unsigned u; } v; v.f = f;
  unsigned r = v.u + 0x7FFFu + ((v.u >> 16) & 1u);
  return (ushort)(r >> 16);
}
__device__ inline unsigned pk2bf(float a, float b) {
  return (unsigned)f2bf(a) | ((unsigned)f2bf(b) << 16);
}
__device__ inline float bf2f(ushort u) {
  union { unsigned u; float f; } v; v.u = ((unsigned)u) << 16; return v.f;
}

// ---------- prep: normalize x -> xn ; transpose x -> xt [B,3,N] ----------
__global__ void k_prep(const float* __restrict__ x, float* __restrict__ xn, float* __restrict__ xt) {
  int i = blockIdx.x * blockDim.x + threadIdx.x;
  if (i >= NB * NP) return;
  int b = i >> 11, n = i & (NP - 1);
  float a0 = x[i * 3 + 0], a1 = x[i * 3 + 1], a2 = x[i * 3 + 2];
  float rn = rsqrtf(a0 * a0 + a1 * a1 + a2 * a2);
  xn[i * 3 + 0] = a0 * rn; xn[i * 3 + 1] = a1 * rn; xn[i * 3 + 2] = a2 * rn;
  float* xb = xt + (size_t)b * 3 * NP;
  xb[0 * NP + n] = a0; xb[1 * NP + n] = a1; xb[2 * NP + n] = a2;
}

__global__ void k_zero1(float* p) { if (threadIdx.x == 0) p[0] = 0.f; }

// ---------- density: binary-search top-32; ballot-based counting (no shfl chain) ----------
__global__ __launch_bounds__(256) void k_density(const float* __restrict__ xn,
                                                 float* __restrict__ inv,
                                                 int* __restrict__ maxinv) {
  int w = threadIdx.x >> 6, lane = threadIdx.x & 63;
  int row = blockIdx.x * 4 + w;
  int b = row >> 11, n = row & (NP - 1);
  const float* xb = xn + (size_t)b * NP * 3;
  float px = xb[n * 3], py = xb[n * 3 + 1], pz = xb[n * 3 + 2];
  float d[32];
  float mn = FLT_MAX, mx = -FLT_MAX;
  #pragma unroll
  for (int k = 0; k < 32; ++k) {
    int m = lane + (k << 6);
    float v = 1.0f - (px * xb[m * 3] + py * xb[m * 3 + 1] + pz * xb[m * 3 + 2]);
    d[k] = v;
    mn = fminf(mn, v); mx = fmaxf(mx, v);
  }
  // lo = global min; hi = min over lanes of per-lane max (>= 32 values below it)
  #pragma unroll
  for (int off = 32; off; off >>= 1) {
    mn = fminf(mn, __shfl_xor(mn, off));
    mx = fminf(mx, __shfl_xor(mx, off));
  }
  float lo = mn, hi = mx + 1e-6f;
  for (int it = 0; it < 28; ++it) {
    float t = 0.5f * (lo + hi);
    int c = 0;
    #pragma unroll
    for (int k = 0; k < 32; ++k) c += (int)__popcll(__ballot(d[k] < t));
    if (c <= 32) lo = t; else hi = t;   // invariant: cnt(<lo)<=32, cnt(<hi)>32
  }
  float s = 0.f; int c = 0;
  #pragma unroll
  for (int k = 0; k < 32; ++k) {
    bool p = d[k] < lo;
    s += p ? d[k] : 0.f;
    c += (int)__popcll(__ballot(p));
  }
  #pragma unroll
  for (int off = 32; off; off >>= 1) s += __shfl_xor(s, off);
  float sum = s + (float)(32 - c) * lo;   // pad remaining picks at threshold
  if (lane == 0) {
    float iv = 32.0f / sum;
    inv[row] = iv;
    atomicMax(maxinv, __float_as_int(iv));
  }
}

__global__ void k_scale(float* __restrict__ dens, const float* __restrict__ maxinv) {
  int i = blockIdx.x * 256 + threadIdx.x;
  if (i < NB * NP) dens[i] *= (1.0f / maxinv[0]);
}

// ---------- attn prep: Ls = (sum wqk^2) * log2(e) ----------
__global__ __launch_bounds__(128) void k_attn_prep(const float* __restrict__ wqk, int D, float* __restrict__ Ls) {
  __shared__ float part[128];
  int t = threadIdx.x;
  float v = (t < D) ? wqk[t] * wqk[t] : 0.f;
  part[t] = v;
  __syncthreads();
  for (int off = 64; off > 0; off >>= 1) {
    if (t < off) part[t] += part[t + off];
    __syncthreads();
  }
  if (t == 0) Ls[0] = part[0] * LOG2E_F;
}

// ---------- E[b][m][n] = exp2(Ls*dm*dn) (bf16), rinv[b][m] = 1/rowsum ----------
__global__ __launch_bounds__(256) void k_expmat(const float* __restrict__ dens,
                                                const float* __restrict__ Lsp,
                                                ushort* __restrict__ E,
                                                float* __restrict__ rinv) {
  int b = blockIdx.x;
  int m = blockIdx.y * 4 + (threadIdx.x >> 6);
  int lane = threadIdx.x & 63;
  const float* db = dens + b * NP;
  float f = Lsp[0] * db[m];
  ushort* Em = E + ((size_t)b * NP + m) * NP;
  float s = 0.f;
  for (int it = 0; it < 8; ++it) {
    int n = it * 256 + lane * 4;
    float4 d = *(const float4*)(db + n);
    float e0 = exp2f(f * d.x), e1 = exp2f(f * d.y), e2 = exp2f(f * d.z), e3 = exp2f(f * d.w);
    s += (e0 + e1) + (e2 + e3);
    ushort4 o; o.x = f2bf(e0); o.y = f2bf(e1); o.z = f2bf(e2); o.w = f2bf(e3);
    *(ushort4*)(Em + n) = o;
  }
  #pragma unroll
  for (int off = 32; off > 0; off >>= 1) s += __shfl_xor(s, off);
  if (lane == 0) rinv[b * NP + m] = 1.0f / s;
}

// ---------- cinv[b][m] = 1/(1e-9 + sum_n E[m][n]*rinv[n])  (E symmetric) ----------
__global__ __launch_bounds__(256) void k_csum(const ushort* __restrict__ E,
                                              const float* __restrict__ rinv,
                                              float* __restrict__ cinv) {
  int b = blockIdx.x;
  int m = blockIdx.y * 4 + (threadIdx.x >> 6);
  int lane = threadIdx.x & 63;
  const ushort* Em = E + ((size_t)b * NP + m) * NP;
  const float* rb = rinv + b * NP;
  float s = 0.f;
  for (int it = 0; it < 8; ++it) {
    int n = it * 256 + lane * 4;
    ushort4 e = *(const ushort4*)(Em + n);
    float4 r = *(const float4*)(rb + n);
    s += bf2f(e.x) * r.x + bf2f(e.y) * r.y + bf2f(e.z) * r.z + bf2f(e.w) * r.w;
  }
  #pragma unroll
  for (int off = 32; off > 0; off >>= 1) s += __shfl_xor(s, off);
  if (lane == 0) cinv[b * NP + m] = 1.0f / (s + 1e-9f);
}

// ---------- x_r via bf16 MFMA ----------
constexpr int LDA = 72;  // bf16 units per LDS row (64 + 8 pad)

__global__ __launch_bounds__(256) void k_xr_mfma(const float* __restrict__ H, float* __restrict__ U,
                                                 const ushort* __restrict__ E,
                                                 const float* __restrict__ rinv,
                                                 const float* __restrict__ cinv, int C) {
  int b = blockIdx.z, m0 = blockIdx.x * 128, c0 = blockIdx.y * 128;
  int tid = threadIdx.x, lane = tid & 63, w = tid >> 6;
  int wr = w >> 1, wc = w & 1;
  const float* Hb = H + (size_t)b * C * NP;
  float* Ub = U + (size_t)b * C * NP;
  const ushort* Eb = E + (size_t)b * NP * NP;
  const float* rb = rinv + b * NP;
  const float* cb = cinv + b * NP;
  __shared__ ushort Asm[128 * LDA];
  __shared__ ushort Bsm[128 * LDA];
  f32x4 acc[4][4];
  #pragma unroll
  for (int i = 0; i < 4; ++i)
    #pragma unroll
    for (int j = 0; j < 4; ++j) acc[i][j] = (f32x4)(0.0f);

  int row = tid >> 1, half = tid & 1;
  for (int n0 = 0; n0 < NP; n0 += 64) {
    __syncthreads();
    {   // A: rows=c (128), cols=n' (64), value H*rinv -> bf16
      const float* src = Hb + (size_t)(c0 + row) * NP + n0 + half * 32;
      const float* rsrc = rb + n0 + half * 32;
      unsigned* dst = (unsigned*)(Asm + row * LDA + half * 32);
      #pragma unroll
      for (int i = 0; i < 8; ++i) {
        float4 hv = *(const float4*)(src + i * 4);
        float4 rv = *(const float4*)(rsrc + i * 4);
        dst[i * 2 + 0] = pk2bf(hv.x * rv.x, hv.y * rv.y);
        dst[i * 2 + 1] = pk2bf(hv.z * rv.z, hv.w * rv.w);
      }
      // B: rows=m' (128), cols=n' (64), E already bf16 [m][n]
      const ushort* esrc = Eb + (size_t)(m0 + row) * NP + n0 + half * 32;
      uint4* bdst = (uint4*)(Bsm + row * LDA + half * 32);
      #pragma unroll
      for (int i = 0; i < 4; ++i) bdst[i] = *(const uint4*)(esrc + i * 8);
    }
    __syncthreads();
    #pragma unroll
    for (int kk = 0; kk < 64; kk += 32) {
      bf16x8 af[4], bfr[4];
      #pragma unroll
      for (int i = 0; i < 4; ++i) {
        af[i]  = *(const bf16x8*)(Asm + (wr * 64 + i * 16 + (lane & 15)) * LDA + kk + (lane >> 4) * 8);
        bfr[i] = *(const bf16x8*)(Bsm + (wc * 64 + i * 16 + (lane & 15)) * LDA + kk + (lane >> 4) * 8);
      }
      #pragma unroll
      for (int i = 0; i < 4; ++i)
        #pragma unroll
        for (int j = 0; j < 4; ++j)
          acc[i][j] = MFMA16(af[i], bfr[j], acc[i][j]);
    }
  }
  #pragma unroll
  for (int j = 0; j < 4; ++j) {
    int m = m0 + wc * 64 + j * 16 + (lane & 15);
    float cm = cb[m];
    #pragma unroll
    for (int i = 0; i < 4; ++i) {
      int c = c0 + wr * 64 + i * 16 + (lane >> 4) * 4;
      #pragma unroll
      for (int r = 0; r < 4; ++r) {
        size_t idx = (size_t)(c + r) * NP + m;
        Ub[idx] = Hb[idx] - cm * acc[i][j][r];
      }
    }
  }
}

// ---------- conv1x1 via bf16 MFMA, with fused BN-stat atomics ----------
__global__ __launch_bounds__(256) void k_gemm_mfma(const float* __restrict__ W,
                                                   const float* __restrict__ IN,
                                                   const float* __restrict__ bias,
                                                   float* __restrict__ OUT,
                                                   int Cin, int Cout,
                                                   float* __restrict__ bn_s,
                                                   float* __restrict__ bn_s2) {
  int b = blockIdx.z, n0 = blockIdx.x * 128, o0 = blockIdx.y * 128;
  int tid = threadIdx.x, lane = tid & 63, w = tid >> 6;
  int wr = w >> 1, wc = w & 1;
  const float* Ib = IN + (size_t)b * Cin * NP;
  float* Ob = OUT + (size_t)b * Cout * NP;
  __shared__ ushort Asm[128 * LDA];
  __shared__ ushort Bsm[128 * LDA];
  f32x4 acc[4][4];
  #pragma unroll
  for (int i = 0; i < 4; ++i)
    #pragma unroll
    for (int j = 0; j < 4; ++j) acc[i][j] = (f32x4)(0.0f);

  int row = tid >> 1, half = tid & 1;
  int csub = tid & 63, q = tid >> 6;
  for (int cc0 = 0; cc0 < Cin; cc0 += 64) {
    __syncthreads();
    {   // A: rows=o (128), cols=c' (64) from W
      const float* src = W + (size_t)(o0 + row) * Cin + cc0 + half * 32;
      unsigned* dst = (unsigned*)(Asm + row * LDA + half * 32);
      #pragma unroll
      for (int i = 0; i < 8; ++i) {
        float4 v = *(const float4*)(src + i * 4);
        dst[i * 2 + 0] = pk2bf(v.x, v.y);
        dst[i * 2 + 1] = pk2bf(v.z, v.w);
      }
      // B: rows=n' (128), cols=c' (64) — transpose of IN[c][n]
      const float* isrc = Ib + (size_t)(cc0 + csub) * NP + n0 + q * 32;
      #pragma unroll
      for (int i = 0; i < 8; ++i) {
        float4 v = *(const float4*)(isrc + i * 4);
        ushort* bd = Bsm + (q * 32 + i * 4) * LDA + csub;
        bd[0]       = f2bf(v.x);
        bd[LDA]     = f2bf(v.y);
        bd[2 * LDA] = f2bf(v.z);
        bd[3 * LDA] = f2bf(v.w);
      }
    }
    __syncthreads();
    #pragma unroll
    for (int kk = 0; kk < 64; kk += 32) {
      bf16x8 af[4], bfr[4];
      #pragma unroll
      for (int i = 0; i < 4; ++i) {
        af[i]  = *(const bf16x8*)(Asm + (wr * 64 + i * 16 + (lane & 15)) * LDA + kk + (lane >> 4) * 8);
        bfr[i] = *(const bf16x8*)(Bsm + (wc * 64 + i * 16 + (lane & 15)) * LDA + kk + (lane >> 4) * 8);
      }
      #pragma unroll
      for (int i = 0; i < 4; ++i)
        #pragma unroll
        for (int j = 0; j < 4; ++j)
          acc[i][j] = MFMA16(af[i], bfr[j], acc[i][j]);
    }
  }
  #pragma unroll
  for (int i = 0; i < 4; ++i) {
    #pragma unroll
    for (int r = 0; r < 4; ++r) {
      int o = o0 + wr * 64 + i * 16 + (lane >> 4) * 4 + r;
      float bv = bias[o];
      float ls = 0.f, ls2 = 0.f;
      #pragma unroll
      for (int j = 0; j < 4; ++j) {
        int n = n0 + wc * 64 + j * 16 + (lane & 15);
        float v = acc[i][j][r] + bv;
        Ob[(size_t)o * NP + n] = v;
        ls += v; ls2 += v * v;
      }
      #pragma unroll
      for (int off = 1; off < 16; off <<= 1) {
        ls  += __shfl_xor(ls, off);
        ls2 += __shfl_xor(ls2, off);
      }
      if ((lane & 15) == 0) {
        atomicAdd(&bn_s[o], ls);
        atomicAdd(&bn_s2[o], ls2);
      }
    }
  }
}

// ---------- fp32 GEMM (conv1 only, Cin=3) ----------
__global__ __launch_bounds__(256) void k_gemm(const float* __restrict__ W,
                                              const float* __restrict__ IN,
                                              const float* __restrict__ bias,
                                              float* __restrict__ OUT,
                                              int Cin, int Cout) {
  int b = blockIdx.z;
  int n0 = blockIdx.x * 64;
  int o0 = blockIdx.y * 64;
  int tid = threadIdx.x;
  int tx = tid & 15, ty = tid >> 4;
  const float* Ib = IN + (size_t)b * Cin * NP;
  float* Ob = OUT + (size_t)b * Cout * NP;
  __shared__ float Wt[64][65];
  __shared__ float It[64][65];
  float acc[4][4] = {};
  for (int c0 = 0; c0 < Cin; c0 += 64) {
    __syncthreads();
    {
      int ci = tid & 63, ob4 = tid >> 6;
      bool cv = (c0 + ci) < Cin;
      #pragma unroll
      for (int k = 0; k < 16; ++k) {
        int oi = ob4 + (k << 2);
        Wt[ci][oi] = cv ? W[(size_t)(o0 + oi) * Cin + c0 + ci] : 0.f;
      }
      int ni = tid & 63, cb4 = tid >> 6;
      #pragma unroll
      for (int k = 0; k < 16; ++k) {
        int ci2 = cb4 + (k << 2);
        It[ci2][ni] = (c0 + ci2) < Cin ? Ib[(size_t)(c0 + ci2) * NP + n0 + ni] : 0.f;
      }
    }
    __syncthreads();
    #pragma unroll 4
    for (int ci = 0; ci < 64; ++ci) {
      float a0 = Wt[ci][ty * 4 + 0], a1 = Wt[ci][ty * 4 + 1], a2 = Wt[ci][ty * 4 + 2], a3 = Wt[ci][ty * 4 + 3];
      float b0 = It[ci][tx * 4 + 0], b1 = It[ci][tx * 4 + 1], b2 = It[ci][tx * 4 + 2], b3 = It[ci][tx * 4 + 3];
      acc[0][0] += a0 * b0; acc[0][1] += a0 * b1; acc[0][2] += a0 * b2; acc[0][3] += a0 * b3;
      acc[1][0] += a1 * b0; acc[1][1] += a1 * b1; acc[1][2] += a1 * b2; acc[1][3] += a1 * b3;
      acc[2][0] += a2 * b0; acc[2][1] += a2 * b1; acc[2][2] += a2 * b2; acc[2][3] += a2 * b3;
      acc[3][0] += a3 * b0; acc[3][1] += a3 * b1; acc[3][2] += a3 * b2; acc[3][3] += a3 * b3;
    }
  }
  #pragma unroll
  for (int i = 0; i < 4; ++i) {
    int o = o0 + ty * 4 + i;
    float bv = bias[o];
    #pragma unroll
    for (int j = 0; j < 4; ++j) {
      int n = n0 + tx * 4 + j;
      Ob[(size_t)o * NP + n] = acc[i][j] + bv;
    }
  }
}

// ---------- BN stats per channel over (B, N)  (conv1 path only) ----------
__global__ __launch_bounds__(256) void k_bnstats(const float* __restrict__ T,
                                                 float* __restrict__ mean,
                                                 float* __restrict__ istd, int C) {
  int c = blockIdx.x;
  int tid = threadIdx.x;
  float s = 0.f, s2 = 0.f;
  for (int b = 0; b < NB; ++b) {
    const float* p = T + ((size_t)b * C + c) * NP;
    for (int n = tid * 4; n < NP; n += 1024) {
      float4 v = *(const float4*)(p + n);
      s += (v.x + v.y) + (v.z + v.w);
      s2 += (v.x * v.x + v.y * v.y) + (v.z * v.z + v.w * v.w);
    }
  }
  __shared__ float rs[256], rs2[256];
  rs[tid] = s; rs2[tid] = s2;
  __syncthreads();
  for (int off = 128; off > 0; off >>= 1) {
    if (tid < off) { rs[tid] += rs[tid + off]; rs2[tid] += rs2[tid + off]; }
    __syncthreads();
  }
  if (tid == 0) {
    float m = rs[0] / (float)(NB * NP);
    float var = rs2[0] / (float)(NB * NP) - m * m;
    mean[c] = m;
    istd[c] = rsqrtf(var + 1e-5f);
  }
}

// ---------- finalize fused stats: (s, s2) -> (mean, istd) ----------
__global__ __launch_bounds__(512) void k_bnfin(const float* __restrict__ bn_s,
                                               const float* __restrict__ bn_s2,
                                               float* __restrict__ mean,
                                               float* __restrict__ istd, int C) {
  int c = threadIdx.x;
  if (c >= C) return;
  float inv = 1.0f / (float)(NB * NP);
  float m = bn_s[c] * inv;
  float var = bn_s2[c] * inv - m * m;
  mean[c] = m;
  istd[c] = rsqrtf(var + 1e-5f);
}

// ---------- BN apply (+optional relu, +optional accumulate), float4 ----------
__global__ __launch_bounds__(256) void k_bnapply(const float4* __restrict__ T, float4* __restrict__ H,
                                                 const float* __restrict__ mean,
                                                 const float* __restrict__ istd,
                                                 int C, int relu, int acc) {
  size_t i = (size_t)blockIdx.x * 256 + threadIdx.x;   // float4 index; NP/4=512 per row
  int c = (int)((i >> 9) % C);
  float m = mean[c], is = istd[c];
  float4 v = T[i];
  v.x = (v.x - m) * is; v.y = (v.y - m) * is; v.z = (v.z - m) * is; v.w = (v.w - m) * is;
  if (relu) {
    v.x = fmaxf(v.x, 0.f); v.y = fmaxf(v.y, 0.f); v.z = fmaxf(v.z, 0.f); v.w = fmaxf(v.w, 0.f);
  }
  if (acc) {
    float4 h = H[i];
    v.x += h.x; v.y += h.y; v.z += h.z; v.w += h.w;
  }
  H[i] = v;
}

// ---------- global max pool over N ----------
__global__ __launch_bounds__(64) void k_maxpool(const float* __restrict__ H, float* __restrict__ g) {
  int bf = blockIdx.x;
  const float* p = H + (size_t)bf * NP;
  int lane = threadIdx.x;
  float mx = -FLT_MAX;
  for (int n = lane; n < NP; n += 64) mx = fmaxf(mx, p[n]);
  #pragma unroll
  for (int off = 32; off > 0; off >>= 1) mx = fmaxf(mx, __shfl_xor(mx, off));
  if (lane == 0) g[bf] = mx;
}

// ---------- MLP head ----------
__global__ __launch_bounds__(256) void k_head(const float* __restrict__ g,
    const float* __restrict__ f1mw, const float* __restrict__ f1mb,
    const float* __restrict__ f2mw, const float* __restrict__ f2mb,
    const float* __restrict__ f3mw, const float* __restrict__ f3mb,
    const float* __restrict__ f1vw, const float* __restrict__ f1vb,
    const float* __restrict__ f2vw, const float* __restrict__ f2vb,
    const float* __restrict__ f3vw, const float* __restrict__ f3vb,
    float* __restrict__ out) {
  bool vpath = (blockIdx.x == 1);
  const float* w1 = vpath ? f1vw : f1mw;
  const float* c1 = vpath ? f1vb : f1mb;
  const float* w2 = vpath ? f2vw : f2mw;
  const float* c2 = vpath ? f2vb : f2mb;
  __shared__ float gg[NB * 512];
  __shared__ float a1[NB * 256];
  __shared__ float a2[NB * 128];
  __shared__ float zz[NB * 128];
  __shared__ float nrm[NB];
  int t = threadIdx.x;
  for (int i = t; i < NB * 512; i += 256) gg[i] = g[i];
  __syncthreads();
  float o[NB];
  {
    #pragma unroll
    for (int b = 0; b < NB; ++b) o[b] = c1[t];
    const float* wr = w1 + (size_t)t * 512;
    for (int j = 0; j < 512; ++j) {
      float w = wr[j];
      #pragma unroll
      for (int b = 0; b < NB; ++b) o[b] += gg[b * 512 + j] * w;
    }
    float mean = 0.f;
    #pragma unroll
    for (int b = 0; b < NB; ++b) mean += o[b];
    mean *= (1.0f / NB);
    float var = 0.f;
    #pragma unroll
    for (int b = 0; b < NB; ++b) { float d = o[b] - mean; var += d * d; }
    var *= (1.0f / NB);
    float is = rsqrtf(var + 1e-5f);
    #pragma unroll
    for (int b = 0; b < NB; ++b) a1[b * 256 + t] = fmaxf((o[b] - mean) * is, 0.f);
  }
  __syncthreads();
  if (t < 128) {
    #pragma unroll
    for (int b = 0; b < NB; ++b) o[b] = c2[t];
    const float* wr = w2 + (size_t)t * 256;
    for (int j = 0; j < 256; ++j) {
      float w = wr[j];
      #pragma unroll
      for (int b = 0; b < NB; ++b) o[b] += a1[b * 256 + j] * w;
    }
    float mean = 0.f;
    #pragma unroll
    for (int b = 0; b < NB; ++b) mean += o[b];
    mean *= (1.0f / NB);
    float var = 0.f;
    #pragma unroll
    for (int b = 0; b < NB; ++b) { float d = o[b] - mean; var += d * d; }
    var *= (1.0f / NB);
    float is = rsqrtf(var + 1e-5f);
    #pragma unroll
    for (int b = 0; b < NB; ++b) a2[b * 128 + t] = fmaxf((o[b] - mean) * is, 0.f);
  }
  __syncthreads();
  if (!vpath) {
    if (t < 128) {
      const float* wr = f3mw + (size_t)t * 128;
      for (int b = 0; b < NB; ++b) {
        float s = f3mb[t];
        for (int j = 0; j < 128; ++j) s += a2[b * 128 + j] * wr[j];
        zz[b * 128 + t] = s;
      }
    }
    __syncthreads();
    if (t < NB) {
      float s = 0.f;
      for (int j = 0; j < 128; ++j) { float v = zz[t * 128 + j]; s += v * v; }
      nrm[t] = sqrtf(s);
    }
    __syncthreads();
    if (t < 128) {
      for (int b = 0; b < NB; ++b) out[b * 128 + t] = zz[b * 128 + t] / nrm[b];
    }
  } else {
    if (t < NB) {
      float s = f3vb[0];
      for (int j = 0; j < 128; ++j) s += a2[t * 128 + j] * f3vw[j];
      float sp = (s > 20.f) ? s : log1pf(expf(s));
      out[NB * 128 + t] = sp + 1.0f;
    }
  }
}

extern "C" void kernel_launch(void* const* d_in, const int* in_sizes, int n_in,
                              void* d_out, int out_size, void* d_ws, size_t ws_size,
                              hipStream_t stream) {
  const float* x  = (const float*)d_in[0];
  const float* w1 = (const float*)d_in[1];
  const float* b1 = (const float*)d_in[2];
  const float* w2 = (const float*)d_in[3];
  const float* b2 = (const float*)d_in[4];
  const float* w3 = (const float*)d_in[5];
  const float* b3 = (const float*)d_in[6];
  const float* w4 = (const float*)d_in[7];
  const float* b4 = (const float*)d_in[8];
  const float* a_wqk[4] = {(const float*)d_in[9],  (const float*)d_in[12], (const float*)d_in[15], (const float*)d_in[18]};
  const float* a_wt[4]  = {(const float*)d_in[10], (const float*)d_in[13], (const float*)d_in[16], (const float*)d_in[19]};
  const float* a_bt[4]  = {(const float*)d_in[11], (const float*)d_in[14], (const float*)d_in[17], (const float*)d_in[20]};
  int a_D[4] = {in_sizes[9], in_sizes[12], in_sizes[15], in_sizes[18]};
  const float* f1mw = (const float*)d_in[21]; const float* f1mb = (const float*)d_in[22];
  const float* f2mw = (const float*)d_in[23]; const float* f2mb = (const float*)d_in[24];
  const float* f3mw = (const float*)d_in[25]; const float* f3mb = (const float*)d_in[26];
  const float* f1vw = (const float*)d_in[27]; const float* f1vb = (const float*)d_in[28];
  const float* f2vw = (const float*)d_in[29]; const float* f2vb = (const float*)d_in[30];
  const float* f3vw = (const float*)d_in[31]; const float* f3vb = (const float*)d_in[32];
  float* out = (float*)d_out;

  float* ws = (float*)d_ws;
  float* xn     = ws; ws += (size_t)NB * NP * 3;
  float* dens   = ws; ws += NB * NP;
  float* maxinv = ws; ws += 16;
  float* Ls     = ws; ws += 16;
  float* rinv   = ws; ws += NB * NP;
  float* cinv   = ws; ws += NB * NP;
  float* bn_m   = ws; ws += 512;
  float* bn_is  = ws; ws += 512;
  float* bn_s   = ws; ws += 512;   // fused-stat accumulators (bn_s, bn_s2 contiguous)
  float* bn_s2  = ws; ws += 512;
  float* g      = ws; ws += NB * 512;
  float* Hb     = ws; ws += (size_t)NB * 512 * NP;
  float* Ub     = ws; ws += (size_t)NB * 512 * NP;
  float* Tb     = ws; ws += (size_t)NB * 512 * NP;
  ushort* E     = (ushort*)Tb;   // E (64MB bf16) aliases Tb (dead when Tb is written)

  k_prep<<<NB * NP / 256, 256, 0, stream>>>(x, xn, Ub);   // Ub temporarily holds x^T [B,3,N]
  k_zero1<<<1, 64, 0, stream>>>(maxinv);
  k_density<<<NB * NP / 4, 256, 0, stream>>>(xn, dens, (int*)maxinv);
  k_scale<<<NB * NP / 256, 256, 0, stream>>>(dens, maxinv);

  auto conv = [&](const float* W, const float* bias, const float* IN, int Cin, int Cout, bool relu) {
    if (Cin < 64) {
      k_gemm<<<dim3(NP / 64, Cout / 64, NB), 256, 0, stream>>>(W, IN, bias, Tb, Cin, Cout);
      k_bnstats<<<Cout, 256, 0, stream>>>(Tb, bn_m, bn_is, Cout);
    } else {
      hipMemsetAsync(bn_s, 0, 1024 * sizeof(float), stream);
      k_gemm_mfma<<<dim3(NP / 128, Cout / 128, NB), 256, 0, stream>>>(W, IN, bias, Tb, Cin, Cout, bn_s, bn_s2);
      k_bnfin<<<1, 512, 0, stream>>>(bn_s, bn_s2, bn_m, bn_is, Cout);
    }
    k_bnapply<<<(int)(((size_t)NB * Cout * NP) / 1024), 256, 0, stream>>>((const float4*)Tb, (float4*)Hb, bn_m, bn_is, Cout, relu ? 1 : 0, 0);
  };
  auto attn = [&](int li, int C) {
    k_attn_prep<<<1, 128, 0, stream>>>(a_wqk[li], a_D[li], Ls);
    k_expmat<<<dim3(NB, NP / 4), 256, 0, stream>>>(dens, Ls, E, rinv);
    k_csum<<<dim3(NB, NP / 4), 256, 0, stream>>>(E, rinv, cinv);
    k_xr_mfma<<<dim3(NP / 128, C / 128, NB), 256, 0, stream>>>(Hb, Ub, E, rinv, cinv, C);
    hipMemsetAsync(bn_s, 0, 1024 * sizeof(float), stream);
    k_gemm_mfma<<<dim3(NP / 128, C / 128, NB), 256, 0, stream>>>(a_wt[li], Ub, a_bt[li], Tb, C, C, bn_s, bn_s2);
    k_bnfin<<<1, 512, 0, stream>>>(bn_s, bn_s2, bn_m, bn_is, C);
    k_bnapply<<<(int)(((size_t)NB * C * NP) / 1024), 256, 0, stream>>>((const float4*)Tb, (float4*)Hb, bn_m, bn_is, C, 1, 1);
  };

  conv(w1, b1, Ub, 3, 128, true);
  attn(0, 128);
  conv(w2, b2, Hb, 128, 128, true);
  attn(1, 128);
  conv(w3, b3, Hb, 128, 256, true);
  attn(2, 256);
  conv(w4, b4, Hb, 256, 512, false);
  attn(3, 512);

  k_maxpool<<<NB * 512, 64, 0, stream>>>(Hb, g);
  k_head<<<2, 256, 0, stream>>>(g, f1mw, f1mb, f2mw, f2mb, f3mw, f3mb,
                                f1vw, f1vb, f2vw, f2vb, f3vw, f3vb, out);
}

// Round 5
// 1015.486 us; speedup vs baseline: 1.2017x; 1.2017x over previous
//
#include <hip/hip_runtime.h>
#include <cfloat>
#include <cmath>

constexpr int NB = 8;
constexpr int NP = 2048;
constexpr float LOG2E_F = 1.4426950408889634f;

typedef __attribute__((ext_vector_type(4))) float f32x4;
typedef __attribute__((ext_vector_type(8))) short bf16x8;
#define MFMA16(a, b, c) __builtin_amdgcn_mfma_f32_16x16x32_bf16(a, b, c, 0, 0, 0)

__device__ inline ushort f2bf(float f) {   // round-to-nearest-even f32 -> bf16
  union { float f; unsigned u; } v; v.f = f;
  unsigned r = v.u + 0x7FFFu + ((v.u >> 16) & 1u);
  return (ushort)(r >> 16);
}
__device__ inline unsigned pk2bf(float a, float b) {
  return (unsigned)f2bf(a) | ((unsigned)f2bf(b) << 16);
}
__device__ inline float bf2f(ushort u) {
  union { unsigned u; float f; } v; v.u = ((unsigned)u) << 16; return v.f;
}

// ---------- prep: normalize x -> xn ; transpose x -> xt [B,3,N] ----------
__global__ void k_prep(const float* __restrict__ x, float* __restrict__ xn, float* __restrict__ xt) {
  int i = blockIdx.x * blockDim.x + threadIdx.x;
  if (i >= NB * NP) return;
  int b = i >> 11, n = i & (NP - 1);
  float a0 = x[i * 3 + 0], a1 = x[i * 3 + 1], a2 = x[i * 3 + 2];
  float rn = rsqrtf(a0 * a0 + a1 * a1 + a2 * a2);
  xn[i * 3 + 0] = a0 * rn; xn[i * 3 + 1] = a1 * rn; xn[i * 3 + 2] = a2 * rn;
  float* xb = xt + (size_t)b * 3 * NP;
  xb[0 * NP + n] = a0; xb[1 * NP + n] = a1; xb[2 * NP + n] = a2;
}

__global__ void k_zero1(float* p) { if (threadIdx.x == 0) p[0] = 0.f; }

// ---------- density: LDS-staged points (SoA), binary-search top-32 ----------
// Block = 512 threads = 8 waves = 8 rows (same batch). Points staged once,
// coalesced, into 3 SoA LDS planes; distance loop is conflict-free ds_reads.
__global__ __launch_bounds__(512) void k_density(const float* __restrict__ xn,
                                                 float* __restrict__ inv,
                                                 int* __restrict__ maxinv) {
  __shared__ float sx[NP], sy[NP], sz[NP];
  int t = threadIdx.x;
  int w = t >> 6, lane = t & 63;
  int row0 = blockIdx.x * 8;
  int b = row0 >> 11;
  const float4* xb4 = (const float4*)(xn + (size_t)b * NP * 3);
  {  // thread t stages points 4t..4t+3 (3 coalesced float4 loads)
    float4 a = xb4[t * 3 + 0], c4 = xb4[t * 3 + 1], e4 = xb4[t * 3 + 2];
    int p = t * 4;
    sx[p + 0] = a.x;  sy[p + 0] = a.y;  sz[p + 0] = a.z;
    sx[p + 1] = a.w;  sy[p + 1] = c4.x; sz[p + 1] = c4.y;
    sx[p + 2] = c4.z; sy[p + 2] = c4.w; sz[p + 2] = e4.x;
    sx[p + 3] = e4.y; sy[p + 3] = e4.z; sz[p + 3] = e4.w;
  }
  __syncthreads();
  int row = row0 + w;
  int n = row & (NP - 1);
  float px = sx[n], py = sy[n], pz = sz[n];   // same addr across wave -> LDS broadcast
  float d[32];
  float mn = FLT_MAX, mx = -FLT_MAX;
  #pragma unroll
  for (int k = 0; k < 32; ++k) {
    int m = lane + (k << 6);   // lane-stride 64 on 32 banks -> 2-way (free)
    float v = 1.0f - (px * sx[m] + py * sy[m] + pz * sz[m]);
    d[k] = v;
    mn = fminf(mn, v); mx = fmaxf(mx, v);
  }
  // lo = global min; hi = min over lanes of per-lane max (>= 32 values below it)
  #pragma unroll
  for (int off = 32; off; off >>= 1) {
    mn = fminf(mn, __shfl_xor(mn, off));
    mx = fminf(mx, __shfl_xor(mx, off));
  }
  float lo = mn, hi = mx + 1e-6f;
  for (int it = 0; it < 28; ++it) {
    float tt = 0.5f * (lo + hi);
    int c = 0;
    #pragma unroll
    for (int k = 0; k < 32; ++k) c += (int)__popcll(__ballot(d[k] < tt));
    if (c <= 32) lo = tt; else hi = tt;   // invariant: cnt(<lo)<=32, cnt(<hi)>32
  }
  float s = 0.f; int c = 0;
  #pragma unroll
  for (int k = 0; k < 32; ++k) {
    bool p = d[k] < lo;
    s += p ? d[k] : 0.f;
    c += (int)__popcll(__ballot(p));
  }
  #pragma unroll
  for (int off = 32; off; off >>= 1) s += __shfl_xor(s, off);
  float sum = s + (float)(32 - c) * lo;   // pad remaining picks at threshold
  if (lane == 0) {
    float iv = 32.0f / sum;
    inv[row] = iv;
    atomicMax(maxinv, __float_as_int(iv));
  }
}

__global__ void k_scale(float* __restrict__ dens, const float* __restrict__ maxinv) {
  int i = blockIdx.x * 256 + threadIdx.x;
  if (i < NB * NP) dens[i] *= (1.0f / maxinv[0]);
}

// ---------- attn prep: Ls = (sum wqk^2) * log2(e) ----------
__global__ __launch_bounds__(128) void k_attn_prep(const float* __restrict__ wqk, int D, float* __restrict__ Ls) {
  __shared__ float part[128];
  int t = threadIdx.x;
  float v = (t < D) ? wqk[t] * wqk[t] : 0.f;
  part[t] = v;
  __syncthreads();
  for (int off = 64; off > 0; off >>= 1) {
    if (t < off) part[t] += part[t + off];
    __syncthreads();
  }
  if (t == 0) Ls[0] = part[0] * LOG2E_F;
}

// ---------- E[b][m][n] = exp2(Ls*dm*dn) (bf16), rinv[b][m] = 1/rowsum ----------
__global__ __launch_bounds__(256) void k_expmat(const float* __restrict__ dens,
                                                const float* __restrict__ Lsp,
                                                ushort* __restrict__ E,
                                                float* __restrict__ rinv) {
  int b = blockIdx.x;
  int m = blockIdx.y * 4 + (threadIdx.x >> 6);
  int lane = threadIdx.x & 63;
  const float* db = dens + b * NP;
  float f = Lsp[0] * db[m];
  ushort* Em = E + ((size_t)b * NP + m) * NP;
  float s = 0.f;
  for (int it = 0; it < 8; ++it) {
    int n = it * 256 + lane * 4;
    float4 d = *(const float4*)(db + n);
    float e0 = exp2f(f * d.x), e1 = exp2f(f * d.y), e2 = exp2f(f * d.z), e3 = exp2f(f * d.w);
    s += (e0 + e1) + (e2 + e3);
    ushort4 o; o.x = f2bf(e0); o.y = f2bf(e1); o.z = f2bf(e2); o.w = f2bf(e3);
    *(ushort4*)(Em + n) = o;
  }
  #pragma unroll
  for (int off = 32; off > 0; off >>= 1) s += __shfl_xor(s, off);
  if (lane == 0) rinv[b * NP + m] = 1.0f / s;
}

// ---------- cinv[b][m] = 1/(1e-9 + sum_n E[m][n]*rinv[n])  (E symmetric) ----------
__global__ __launch_bounds__(256) void k_csum(const ushort* __restrict__ E,
                                              const float* __restrict__ rinv,
                                              float* __restrict__ cinv) {
  int b = blockIdx.x;
  int m = blockIdx.y * 4 + (threadIdx.x >> 6);
  int lane = threadIdx.x & 63;
  const ushort* Em = E + ((size_t)b * NP + m) * NP;
  const float* rb = rinv + b * NP;
  float s = 0.f;
  for (int it = 0; it < 8; ++it) {
    int n = it * 256 + lane * 4;
    ushort4 e = *(const ushort4*)(Em + n);
    float4 r = *(const float4*)(rb + n);
    s += bf2f(e.x) * r.x + bf2f(e.y) * r.y + bf2f(e.z) * r.z + bf2f(e.w) * r.w;
  }
  #pragma unroll
  for (int off = 32; off > 0; off >>= 1) s += __shfl_xor(s, off);
  if (lane == 0) cinv[b * NP + m] = 1.0f / (s + 1e-9f);
}

// ---------- x_r via bf16 MFMA ----------
constexpr int LDA = 72;  // bf16 units per LDS row (64 + 8 pad)

__global__ __launch_bounds__(256) void k_xr_mfma(const float* __restrict__ H, float* __restrict__ U,
                                                 const ushort* __restrict__ E,
                                                 const float* __restrict__ rinv,
                                                 const float* __restrict__ cinv, int C) {
  int b = blockIdx.z, m0 = blockIdx.x * 128, c0 = blockIdx.y * 128;
  int tid = threadIdx.x, lane = tid & 63, w = tid >> 6;
  int wr = w >> 1, wc = w & 1;
  const float* Hb = H + (size_t)b * C * NP;
  float* Ub = U + (size_t)b * C * NP;
  const ushort* Eb = E + (size_t)b * NP * NP;
  const float* rb = rinv + b * NP;
  const float* cb = cinv + b * NP;
  __shared__ ushort Asm[128 * LDA];
  __shared__ ushort Bsm[128 * LDA];
  f32x4 acc[4][4];
  #pragma unroll
  for (int i = 0; i < 4; ++i)
    #pragma unroll
    for (int j = 0; j < 4; ++j) acc[i][j] = (f32x4)(0.0f);

  int row = tid >> 1, half = tid & 1;
  for (int n0 = 0; n0 < NP; n0 += 64) {
    __syncthreads();
    {   // A: rows=c (128), cols=n' (64), value H*rinv -> bf16
      const float* src = Hb + (size_t)(c0 + row) * NP + n0 + half * 32;
      const float* rsrc = rb + n0 + half * 32;
      unsigned* dst = (unsigned*)(Asm + row * LDA + half * 32);
      #pragma unroll
      for (int i = 0; i < 8; ++i) {
        float4 hv = *(const float4*)(src + i * 4);
        float4 rv = *(const float4*)(rsrc + i * 4);
        dst[i * 2 + 0] = pk2bf(hv.x * rv.x, hv.y * rv.y);
        dst[i * 2 + 1] = pk2bf(hv.z * rv.z, hv.w * rv.w);
      }
      // B: rows=m' (128), cols=n' (64), E already bf16 [m][n]
      const ushort* esrc = Eb + (size_t)(m0 + row) * NP + n0 + half * 32;
      uint4* bdst = (uint4*)(Bsm + row * LDA + half * 32);
      #pragma unroll
      for (int i = 0; i < 4; ++i) bdst[i] = *(const uint4*)(esrc + i * 8);
    }
    __syncthreads();
    #pragma unroll
    for (int kk = 0; kk < 64; kk += 32) {
      bf16x8 af[4], bfr[4];
      #pragma unroll
      for (int i = 0; i < 4; ++i) {
        af[i]  = *(const bf16x8*)(Asm + (wr * 64 + i * 16 + (lane & 15)) * LDA + kk + (lane >> 4) * 8);
        bfr[i] = *(const bf16x8*)(Bsm + (wc * 64 + i * 16 + (lane & 15)) * LDA + kk + (lane >> 4) * 8);
      }
      #pragma unroll
      for (int i = 0; i < 4; ++i)
        #pragma unroll
        for (int j = 0; j < 4; ++j)
          acc[i][j] = MFMA16(af[i], bfr[j], acc[i][j]);
    }
  }
  #pragma unroll
  for (int j = 0; j < 4; ++j) {
    int m = m0 + wc * 64 + j * 16 + (lane & 15);
    float cm = cb[m];
    #pragma unroll
    for (int i = 0; i < 4; ++i) {
      int c = c0 + wr * 64 + i * 16 + (lane >> 4) * 4;
      #pragma unroll
      for (int r = 0; r < 4; ++r) {
        size_t idx = (size_t)(c + r) * NP + m;
        Ub[idx] = Hb[idx] - cm * acc[i][j][r];
      }
    }
  }
}

// ---------- conv1x1 via bf16 MFMA ----------
__global__ __launch_bounds__(256) void k_gemm_mfma(const float* __restrict__ W,
                                                   const float* __restrict__ IN,
                                                   const float* __restrict__ bias,
                                                   float* __restrict__ OUT,
                                                   int Cin, int Cout) {
  int b = blockIdx.z, n0 = blockIdx.x * 128, o0 = blockIdx.y * 128;
  int tid = threadIdx.x, lane = tid & 63, w = tid >> 6;
  int wr = w >> 1, wc = w & 1;
  const float* Ib = IN + (size_t)b * Cin * NP;
  float* Ob = OUT + (size_t)b * Cout * NP;
  __shared__ ushort Asm[128 * LDA];
  __shared__ ushort Bsm[128 * LDA];
  f32x4 acc[4][4];
  #pragma unroll
  for (int i = 0; i < 4; ++i)
    #pragma unroll
    for (int j = 0; j < 4; ++j) acc[i][j] = (f32x4)(0.0f);

  int row = tid >> 1, half = tid & 1;
  int csub = tid & 63, q = tid >> 6;
  for (int cc0 = 0; cc0 < Cin; cc0 += 64) {
    __syncthreads();
    {   // A: rows=o (128), cols=c' (64) from W
      const float* src = W + (size_t)(o0 + row) * Cin + cc0 + half * 32;
      unsigned* dst = (unsigned*)(Asm + row * LDA + half * 32);
      #pragma unroll
      for (int i = 0; i < 8; ++i) {
        float4 v = *(const float4*)(src + i * 4);
        dst[i * 2 + 0] = pk2bf(v.x, v.y);
        dst[i * 2 + 1] = pk2bf(v.z, v.w);
      }
      // B: rows=n' (128), cols=c' (64) — transpose of IN[c][n]
      const float* isrc = Ib + (size_t)(cc0 + csub) * NP + n0 + q * 32;
      #pragma unroll
      for (int i = 0; i < 8; ++i) {
        float4 v = *(const float4*)(isrc + i * 4);
        ushort* bd = Bsm + (q * 32 + i * 4) * LDA + csub;
        bd[0]       = f2bf(v.x);
        bd[LDA]     = f2bf(v.y);
        bd[2 * LDA] = f2bf(v.z);
        bd[3 * LDA] = f2bf(v.w);
      }
    }
    __syncthreads();
    #pragma unroll
    for (int kk = 0; kk < 64; kk += 32) {
      bf16x8 af[4], bfr[4];
      #pragma unroll
      for (int i = 0; i < 4; ++i) {
        af[i]  = *(const bf16x8*)(Asm + (wr * 64 + i * 16 + (lane & 15)) * LDA + kk + (lane >> 4) * 8);
        bfr[i] = *(const bf16x8*)(Bsm + (wc * 64 + i * 16 + (lane & 15)) * LDA + kk + (lane >> 4) * 8);
      }
      #pragma unroll
      for (int i = 0; i < 4; ++i)
        #pragma unroll
        for (int j = 0; j < 4; ++j)
          acc[i][j] = MFMA16(af[i], bfr[j], acc[i][j]);
    }
  }
  #pragma unroll
  for (int i = 0; i < 4; ++i) {
    #pragma unroll
    for (int r = 0; r < 4; ++r) {
      int o = o0 + wr * 64 + i * 16 + (lane >> 4) * 4 + r;
      float bv = bias[o];
      #pragma unroll
      for (int j = 0; j < 4; ++j) {
        int n = n0 + wc * 64 + j * 16 + (lane & 15);
        Ob[(size_t)o * NP + n] = acc[i][j][r] + bv;
      }
    }
  }
}

// ---------- fp32 GEMM (conv1 only, Cin=3) ----------
__global__ __launch_bounds__(256) void k_gemm(const float* __restrict__ W,
                                              const float* __restrict__ IN,
                                              const float* __restrict__ bias,
                                              float* __restrict__ OUT,
                                              int Cin, int Cout) {
  int b = blockIdx.z;
  int n0 = blockIdx.x * 64;
  int o0 = blockIdx.y * 64;
  int tid = threadIdx.x;
  int tx = tid & 15, ty = tid >> 4;
  const float* Ib = IN + (size_t)b * Cin * NP;
  float* Ob = OUT + (size_t)b * Cout * NP;
  __shared__ float Wt[64][65];
  __shared__ float It[64][65];
  float acc[4][4] = {};
  for (int c0 = 0; c0 < Cin; c0 += 64) {
    __syncthreads();
    {
      int ci = tid & 63, ob4 = tid >> 6;
      bool cv = (c0 + ci) < Cin;
      #pragma unroll
      for (int k = 0; k < 16; ++k) {
        int oi = ob4 + (k << 2);
        Wt[ci][oi] = cv ? W[(size_t)(o0 + oi) * Cin + c0 + ci] : 0.f;
      }
      int ni = tid & 63, cb4 = tid >> 6;
      #pragma unroll
      for (int k = 0; k < 16; ++k) {
        int ci2 = cb4 + (k << 2);
        It[ci2][ni] = (c0 + ci2) < Cin ? Ib[(size_t)(c0 + ci2) * NP + n0 + ni] : 0.f;
      }
    }
    __syncthreads();
    #pragma unroll 4
    for (int ci = 0; ci < 64; ++ci) {
      float a0 = Wt[ci][ty * 4 + 0], a1 = Wt[ci][ty * 4 + 1], a2 = Wt[ci][ty * 4 + 2], a3 = Wt[ci][ty * 4 + 3];
      float b0 = It[ci][tx * 4 + 0], b1 = It[ci][tx * 4 + 1], b2 = It[ci][tx * 4 + 2], b3 = It[ci][tx * 4 + 3];
      acc[0][0] += a0 * b0; acc[0][1] += a0 * b1; acc[0][2] += a0 * b2; acc[0][3] += a0 * b3;
      acc[1][0] += a1 * b0; acc[1][1] += a1 * b1; acc[1][2] += a1 * b2; acc[1][3] += a1 * b3;
      acc[2][0] += a2 * b0; acc[2][1] += a2 * b1; acc[2][2] += a2 * b2; acc[2][3] += a2 * b3;
      acc[3][0] += a3 * b0; acc[3][1] += a3 * b1; acc[3][2] += a3 * b2; acc[3][3] += a3 * b3;
    }
  }
  #pragma unroll
  for (int i = 0; i < 4; ++i) {
    int o = o0 + ty * 4 + i;
    float bv = bias[o];
    #pragma unroll
    for (int j = 0; j < 4; ++j) {
      int n = n0 + tx * 4 + j;
      Ob[(size_t)o * NP + n] = acc[i][j] + bv;
    }
  }
}

// ---------- BN stats per channel over (B, N) ----------
__global__ __launch_bounds__(256) void k_bnstats(const float* __restrict__ T,
                                                 float* __restrict__ mean,
                                                 float* __restrict__ istd, int C) {
  int c = blockIdx.x;
  int tid = threadIdx.x;
  float s = 0.f, s2 = 0.f;
  for (int b = 0; b < NB; ++b) {
    const float* p = T + ((size_t)b * C + c) * NP;
    for (int n = tid * 4; n < NP; n += 1024) {
      float4 v = *(const float4*)(p + n);
      s += (v.x + v.y) + (v.z + v.w);
      s2 += (v.x * v.x + v.y * v.y) + (v.z * v.z + v.w * v.w);
    }
  }
  __shared__ float rs[256], rs2[256];
  rs[tid] = s; rs2[tid] = s2;
  __syncthreads();
  for (int off = 128; off > 0; off >>= 1) {
    if (tid < off) { rs[tid] += rs[tid + off]; rs2[tid] += rs2[tid + off]; }
    __syncthreads();
  }
  if (tid == 0) {
    float m = rs[0] / (float)(NB * NP);
    float var = rs2[0] / (float)(NB * NP) - m * m;
    mean[c] = m;
    istd[c] = rsqrtf(var + 1e-5f);
  }
}

// ---------- BN apply (+optional relu, +optional accumulate), float4 ----------
__global__ __launch_bounds__(256) void k_bnapply(const float4* __restrict__ T, float4* __restrict__ H,
                                                 const float* __restrict__ mean,
                                                 const float* __restrict__ istd,
                                                 int C, int relu, int acc) {
  size_t i = (size_t)blockIdx.x * 256 + threadIdx.x;   // float4 index; NP/4=512 per row
  int c = (int)((i >> 9) % C);
  float m = mean[c], is = istd[c];
  float4 v = T[i];
  v.x = (v.x - m) * is; v.y = (v.y - m) * is; v.z = (v.z - m) * is; v.w = (v.w - m) * is;
  if (relu) {
    v.x = fmaxf(v.x, 0.f); v.y = fmaxf(v.y, 0.f); v.z = fmaxf(v.z, 0.f); v.w = fmaxf(v.w, 0.f);
  }
  if (acc) {
    float4 h = H[i];
    v.x += h.x; v.y += h.y; v.z += h.z; v.w += h.w;
  }
  H[i] = v;
}

// ---------- global max pool over N ----------
__global__ __launch_bounds__(64) void k_maxpool(const float* __restrict__ H, float* __restrict__ g) {
  int bf = blockIdx.x;
  const float* p = H + (size_t)bf * NP;
  int lane = threadIdx.x;
  float mx = -FLT_MAX;
  for (int n = lane; n < NP; n += 64) mx = fmaxf(mx, p[n]);
  #pragma unroll
  for (int off = 32; off > 0; off >>= 1) mx = fmaxf(mx, __shfl_xor(mx, off));
  if (lane == 0) g[bf] = mx;
}

// ---------- MLP head ----------
__global__ __launch_bounds__(256) void k_head(const float* __restrict__ g,
    const float* __restrict__ f1mw, const float* __restrict__ f1mb,
    const float* __restrict__ f2mw, const float* __restrict__ f2mb,
    const float* __restrict__ f3mw, const float* __restrict__ f3mb,
    const float* __restrict__ f1vw, const float* __restrict__ f1vb,
    const float* __restrict__ f2vw, const float* __restrict__ f2vb,
    const float* __restrict__ f3vw, const float* __restrict__ f3vb,
    float* __restrict__ out) {
  bool vpath = (blockIdx.x == 1);
  const float* w1 = vpath ? f1vw : f1mw;
  const float* c1 = vpath ? f1vb : f1mb;
  const float* w2 = vpath ? f2vw : f2mw;
  const float* c2 = vpath ? f2vb : f2mb;
  __shared__ float gg[NB * 512];
  __shared__ float a1[NB * 256];
  __shared__ float a2[NB * 128];
  __shared__ float zz[NB * 128];
  __shared__ float nrm[NB];
  int t = threadIdx.x;
  for (int i = t; i < NB * 512; i += 256) gg[i] = g[i];
  __syncthreads();
  float o[NB];
  {
    #pragma unroll
    for (int b = 0; b < NB; ++b) o[b] = c1[t];
    const float* wr = w1 + (size_t)t * 512;
    for (int j = 0; j < 512; ++j) {
      float w = wr[j];
      #pragma unroll
      for (int b = 0; b < NB; ++b) o[b] += gg[b * 512 + j] * w;
    }
    float mean = 0.f;
    #pragma unroll
    for (int b = 0; b < NB; ++b) mean += o[b];
    mean *= (1.0f / NB);
    float var = 0.f;
    #pragma unroll
    for (int b = 0; b < NB; ++b) { float d = o[b] - mean; var += d * d; }
    var *= (1.0f / NB);
    float is = rsqrtf(var + 1e-5f);
    #pragma unroll
    for (int b = 0; b < NB; ++b) a1[b * 256 + t] = fmaxf((o[b] - mean) * is, 0.f);
  }
  __syncthreads();
  if (t < 128) {
    #pragma unroll
    for (int b = 0; b < NB; ++b) o[b] = c2[t];
    const float* wr = w2 + (size_t)t * 256;
    for (int j = 0; j < 256; ++j) {
      float w = wr[j];
      #pragma unroll
      for (int b = 0; b < NB; ++b) o[b] += a1[b * 256 + j] * w;
    }
    float mean = 0.f;
    #pragma unroll
    for (int b = 0; b < NB; ++b) mean += o[b];
    mean *= (1.0f / NB);
    float var = 0.f;
    #pragma unroll
    for (int b = 0; b < NB; ++b) { float d = o[b] - mean; var += d * d; }
    var *= (1.0f / NB);
    float is = rsqrtf(var + 1e-5f);
    #pragma unroll
    for (int b = 0; b < NB; ++b) a2[b * 128 + t] = fmaxf((o[b] - mean) * is, 0.f);
  }
  __syncthreads();
  if (!vpath) {
    if (t < 128) {
      const float* wr = f3mw + (size_t)t * 128;
      for (int b = 0; b < NB; ++b) {
        float s = f3mb[t];
        for (int j = 0; j < 128; ++j) s += a2[b * 128 + j] * wr[j];
        zz[b * 128 + t] = s;
      }
    }
    __syncthreads();
    if (t < NB) {
      float s = 0.f;
      for (int j = 0; j < 128; ++j) { float v = zz[t * 128 + j]; s += v * v; }
      nrm[t] = sqrtf(s);
    }
    __syncthreads();
    if (t < 128) {
      for (int b = 0; b < NB; ++b) out[b * 128 + t] = zz[b * 128 + t] / nrm[b];
    }
  } else {
    if (t < NB) {
      float s = f3vb[0];
      for (int j = 0; j < 128; ++j) s += a2[t * 128 + j] * f3vw[j];
      float sp = (s > 20.f) ? s : log1pf(expf(s));
      out[NB * 128 + t] = sp + 1.0f;
    }
  }
}

extern "C" void kernel_launch(void* const* d_in, const int* in_sizes, int n_in,
                              void* d_out, int out_size, void* d_ws, size_t ws_size,
                              hipStream_t stream) {
  const float* x  = (const float*)d_in[0];
  const float* w1 = (const float*)d_in[1];
  const float* b1 = (const float*)d_in[2];
  const float* w2 = (const float*)d_in[3];
  const float* b2 = (const float*)d_in[4];
  const float* w3 = (const float*)d_in[5];
  const float* b3 = (const float*)d_in[6];
  const float* w4 = (const float*)d_in[7];
  const float* b4 = (const float*)d_in[8];
  const float* a_wqk[4] = {(const float*)d_in[9],  (const float*)d_in[12], (const float*)d_in[15], (const float*)d_in[18]};
  const float* a_wt[4]  = {(const float*)d_in[10], (const float*)d_in[13], (const float*)d_in[16], (const float*)d_in[19]};
  const float* a_bt[4]  = {(const float*)d_in[11], (const float*)d_in[14], (const float*)d_in[17], (const float*)d_in[20]};
  int a_D[4] = {in_sizes[9], in_sizes[12], in_sizes[15], in_sizes[18]};
  const float* f1mw = (const float*)d_in[21]; const float* f1mb = (const float*)d_in[22];
  const float* f2mw = (const float*)d_in[23]; const float* f2mb = (const float*)d_in[24];
  const float* f3mw = (const float*)d_in[25]; const float* f3mb = (const float*)d_in[26];
  const float* f1vw = (const float*)d_in[27]; const float* f1vb = (const float*)d_in[28];
  const float* f2vw = (const float*)d_in[29]; const float* f2vb = (const float*)d_in[30];
  const float* f3vw = (const float*)d_in[31]; const float* f3vb = (const float*)d_in[32];
  float* out = (float*)d_out;

  float* ws = (float*)d_ws;
  float* xn     = ws; ws += (size_t)NB * NP * 3;
  float* dens   = ws; ws += NB * NP;
  float* maxinv = ws; ws += 16;
  float* Ls     = ws; ws += 16;
  float* rinv   = ws; ws += NB * NP;
  float* cinv   = ws; ws += NB * NP;
  float* bn_m   = ws; ws += 512;
  float* bn_is  = ws; ws += 512;
  float* g      = ws; ws += NB * 512;
  float* Hb     = ws; ws += (size_t)NB * 512 * NP;
  float* Ub     = ws; ws += (size_t)NB * 512 * NP;
  float* Tb     = ws; ws += (size_t)NB * 512 * NP;
  ushort* E     = (ushort*)Tb;   // E (64MB bf16) aliases Tb (dead when Tb is written)

  k_prep<<<NB * NP / 256, 256, 0, stream>>>(x, xn, Ub);   // Ub temporarily holds x^T [B,3,N]
  k_zero1<<<1, 64, 0, stream>>>(maxinv);
  k_density<<<NB * NP / 8, 512, 0, stream>>>(xn, dens, (int*)maxinv);
  k_scale<<<NB * NP / 256, 256, 0, stream>>>(dens, maxinv);

  auto conv = [&](const float* W, const float* bias, const float* IN, int Cin, int Cout, bool relu) {
    if (Cin < 64)
      k_gemm<<<dim3(NP / 64, Cout / 64, NB), 256, 0, stream>>>(W, IN, bias, Tb, Cin, Cout);
    else
      k_gemm_mfma<<<dim3(NP / 128, Cout / 128, NB), 256, 0, stream>>>(W, IN, bias, Tb, Cin, Cout);
    k_bnstats<<<Cout, 256, 0, stream>>>(Tb, bn_m, bn_is, Cout);
    k_bnapply<<<(int)(((size_t)NB * Cout * NP) / 1024), 256, 0, stream>>>((const float4*)Tb, (float4*)Hb, bn_m, bn_is, Cout, relu ? 1 : 0, 0);
  };
  auto attn = [&](int li, int C) {
    k_attn_prep<<<1, 128, 0, stream>>>(a_wqk[li], a_D[li], Ls);
    k_expmat<<<dim3(NB, NP / 4), 256, 0, stream>>>(dens, Ls, E, rinv);
    k_csum<<<dim3(NB, NP / 4), 256, 0, stream>>>(E, rinv, cinv);
    k_xr_mfma<<<dim3(NP / 128, C / 128, NB), 256, 0, stream>>>(Hb, Ub, E, rinv, cinv, C);
    k_gemm_mfma<<<dim3(NP / 128, C / 128, NB), 256, 0, stream>>>(a_wt[li], Ub, a_bt[li], Tb, C, C);
    k_bnstats<<<C, 256, 0, stream>>>(Tb, bn_m, bn_is, C);
    k_bnapply<<<(int)(((size_t)NB * C * NP) / 1024), 256, 0, stream>>>((const float4*)Tb, (float4*)Hb, bn_m, bn_is, C, 1, 1);
  };

  conv(w1, b1, Ub, 3, 128, true);
  attn(0, 128);
  conv(w2, b2, Hb, 128, 128, true);
  attn(1, 128);
  conv(w3, b3, Hb, 128, 256, true);
  attn(2, 256);
  conv(w4, b4, Hb, 256, 512, false);
  attn(3, 512);

  k_maxpool<<<NB * 512, 64, 0, stream>>>(Hb, g);
  k_head<<<2, 256, 0, stream>>>(g, f1mw, f1mb, f2mw, f2mb, f3mw, f3mb,
                                f1vw, f1vb, f2vw, f2vb, f3vw, f3vb, out);
}

// Round 6
// 1010.630 us; speedup vs baseline: 1.2074x; 1.0048x over previous
//
#include <hip/hip_runtime.h>
#include <cfloat>
#include <cmath>

constexpr int NB = 8;
constexpr int NP = 2048;
constexpr float LOG2E_F = 1.4426950408889634f;

typedef __attribute__((ext_vector_type(4))) float f32x4;
typedef __attribute__((ext_vector_type(8))) short bf16x8;
#define MFMA16(a, b, c) __builtin_amdgcn_mfma_f32_16x16x32_bf16(a, b, c, 0, 0, 0)

__device__ inline ushort f2bf(float f) {   // round-to-nearest-even f32 -> bf16
  union { float f; unsigned u; } v; v.f = f;
  unsigned r = v.u + 0x7FFFu + ((v.u >> 16) & 1u);
  return (ushort)(r >> 16);
}
__device__ inline unsigned pk2bf(float a, float b) {
  return (unsigned)f2bf(a) | ((unsigned)f2bf(b) << 16);
}
__device__ inline float bf2f(ushort u) {
  union { unsigned u; float f; } v; v.u = ((unsigned)u) << 16; return v.f;
}

// Full-wave i32 sum via VALU DPP (no SALU chain, no DS): row_shr 1/2/4/8 then
// row_bcast 15/31; total lands in lane 63, returned wave-uniform via readlane.
__device__ inline int dpp_wave_sum_i32(int c) {
  c += __builtin_amdgcn_update_dpp(0, c, 0x111, 0xf, 0xf, true);  // row_shr:1
  c += __builtin_amdgcn_update_dpp(0, c, 0x112, 0xf, 0xf, true);  // row_shr:2
  c += __builtin_amdgcn_update_dpp(0, c, 0x114, 0xf, 0xf, true);  // row_shr:4
  c += __builtin_amdgcn_update_dpp(0, c, 0x118, 0xf, 0xf, true);  // row_shr:8
  c += __builtin_amdgcn_update_dpp(0, c, 0x142, 0xf, 0xf, true);  // row_bcast:15
  c += __builtin_amdgcn_update_dpp(0, c, 0x143, 0xf, 0xf, true);  // row_bcast:31
  return __builtin_amdgcn_readlane(c, 63);
}

// ---------- prep: normalize x -> xn ; transpose x -> xt [B,3,N] ----------
__global__ void k_prep(const float* __restrict__ x, float* __restrict__ xn, float* __restrict__ xt) {
  int i = blockIdx.x * blockDim.x + threadIdx.x;
  if (i >= NB * NP) return;
  int b = i >> 11, n = i & (NP - 1);
  float a0 = x[i * 3 + 0], a1 = x[i * 3 + 1], a2 = x[i * 3 + 2];
  float rn = rsqrtf(a0 * a0 + a1 * a1 + a2 * a2);
  xn[i * 3 + 0] = a0 * rn; xn[i * 3 + 1] = a1 * rn; xn[i * 3 + 2] = a2 * rn;
  float* xb = xt + (size_t)b * 3 * NP;
  xb[0 * NP + n] = a0; xb[1 * NP + n] = a1; xb[2 * NP + n] = a2;
}

__global__ void k_zero1(float* p) { if (threadIdx.x == 0) p[0] = 0.f; }

// ---------- density: LDS-staged SoA points; binary-search top-32 with
// all-VALU counting (v_cmp+addc per elem, DPP wave reduce) ----------
__global__ __launch_bounds__(512) void k_density(const float* __restrict__ xn,
                                                 float* __restrict__ inv,
                                                 int* __restrict__ maxinv) {
  __shared__ float sx[NP], sy[NP], sz[NP];
  int t = threadIdx.x;
  int w = t >> 6, lane = t & 63;
  int row0 = blockIdx.x * 8;
  int b = row0 >> 11;
  const float4* xb4 = (const float4*)(xn + (size_t)b * NP * 3);
  {  // thread t stages points 4t..4t+3 (3 coalesced float4 loads)
    float4 a = xb4[t * 3 + 0], c4 = xb4[t * 3 + 1], e4 = xb4[t * 3 + 2];
    int p = t * 4;
    sx[p + 0] = a.x;  sy[p + 0] = a.y;  sz[p + 0] = a.z;
    sx[p + 1] = a.w;  sy[p + 1] = c4.x; sz[p + 1] = c4.y;
    sx[p + 2] = c4.z; sy[p + 2] = c4.w; sz[p + 2] = e4.x;
    sx[p + 3] = e4.y; sy[p + 3] = e4.z; sz[p + 3] = e4.w;
  }
  __syncthreads();
  int row = row0 + w;
  int n = row & (NP - 1);
  float px = sx[n], py = sy[n], pz = sz[n];   // same addr across wave -> LDS broadcast
  float d[32];
  float mn = FLT_MAX, mx = -FLT_MAX;
  #pragma unroll
  for (int k = 0; k < 32; ++k) {
    int m = lane + (k << 6);   // lane-stride 64 on 32 banks -> 2-way (free)
    float v = 1.0f - (px * sx[m] + py * sy[m] + pz * sz[m]);
    d[k] = v;
    mn = fminf(mn, v); mx = fmaxf(mx, v);
  }
  // lo = global min; hi = min over lanes of per-lane max (>= 32 values below it)
  #pragma unroll
  for (int off = 32; off; off >>= 1) {
    mn = fminf(mn, __shfl_xor(mn, off));
    mx = fminf(mx, __shfl_xor(mx, off));
  }
  float lo = mn, hi = mx + 1e-6f;
  for (int it = 0; it < 24; ++it) {
    float tt = 0.5f * (lo + hi);
    int c = 0;
    #pragma unroll
    for (int k = 0; k < 32; ++k) c += (d[k] < tt) ? 1 : 0;   // v_cmp + v_addc (VALU)
    int ctot = dpp_wave_sum_i32(c);
    if (ctot <= 32) lo = tt; else hi = tt;   // invariant: cnt(<lo)<=32, cnt(<hi)>32
  }
  float s = 0.f; int c = 0;
  #pragma unroll
  for (int k = 0; k < 32; ++k) {
    bool p = d[k] < lo;
    s += p ? d[k] : 0.f;
    c += p ? 1 : 0;
  }
  int ctot = dpp_wave_sum_i32(c);
  #pragma unroll
  for (int off = 32; off; off >>= 1) s += __shfl_xor(s, off);
  float sum = s + (float)(32 - ctot) * lo;   // pad remaining picks at threshold
  if (lane == 0) {
    float iv = 32.0f / sum;
    inv[row] = iv;
    atomicMax(maxinv, __float_as_int(iv));
  }
}

__global__ void k_scale(float* __restrict__ dens, const float* __restrict__ maxinv) {
  int i = blockIdx.x * 256 + threadIdx.x;
  if (i < NB * NP) dens[i] *= (1.0f / maxinv[0]);
}

// ---------- attn prep: Ls = (sum wqk^2) * log2(e) ----------
__global__ __launch_bounds__(128) void k_attn_prep(const float* __restrict__ wqk, int D, float* __restrict__ Ls) {
  __shared__ float part[128];
  int t = threadIdx.x;
  float v = (t < D) ? wqk[t] * wqk[t] : 0.f;
  part[t] = v;
  __syncthreads();
  for (int off = 64; off > 0; off >>= 1) {
    if (t < off) part[t] += part[t + off];
    __syncthreads();
  }
  if (t == 0) Ls[0] = part[0] * LOG2E_F;
}

// ---------- E[b][m][n] = exp2(Ls*dm*dn) (bf16), rinv[b][m] = 1/rowsum ----------
__global__ __launch_bounds__(256) void k_expmat(const float* __restrict__ dens,
                                                const float* __restrict__ Lsp,
                                                ushort* __restrict__ E,
                                                float* __restrict__ rinv) {
  int b = blockIdx.x;
  int m = blockIdx.y * 4 + (threadIdx.x >> 6);
  int lane = threadIdx.x & 63;
  const float* db = dens + b * NP;
  float f = Lsp[0] * db[m];
  ushort* Em = E + ((size_t)b * NP + m) * NP;
  float s = 0.f;
  for (int it = 0; it < 8; ++it) {
    int n = it * 256 + lane * 4;
    float4 d = *(const float4*)(db + n);
    float e0 = exp2f(f * d.x), e1 = exp2f(f * d.y), e2 = exp2f(f * d.z), e3 = exp2f(f * d.w);
    s += (e0 + e1) + (e2 + e3);
    ushort4 o; o.x = f2bf(e0); o.y = f2bf(e1); o.z = f2bf(e2); o.w = f2bf(e3);
    *(ushort4*)(Em + n) = o;
  }
  #pragma unroll
  for (int off = 32; off > 0; off >>= 1) s += __shfl_xor(s, off);
  if (lane == 0) rinv[b * NP + m] = 1.0f / s;
}

// ---------- cinv[b][m] = 1/(1e-9 + sum_n E[m][n]*rinv[n])  (E symmetric) ----------
__global__ __launch_bounds__(256) void k_csum(const ushort* __restrict__ E,
                                              const float* __restrict__ rinv,
                                              float* __restrict__ cinv) {
  int b = blockIdx.x;
  int m = blockIdx.y * 4 + (threadIdx.x >> 6);
  int lane = threadIdx.x & 63;
  const ushort* Em = E + ((size_t)b * NP + m) * NP;
  const float* rb = rinv + b * NP;
  float s = 0.f;
  for (int it = 0; it < 8; ++it) {
    int n = it * 256 + lane * 4;
    ushort4 e = *(const ushort4*)(Em + n);
    float4 r = *(const float4*)(rb + n);
    s += bf2f(e.x) * r.x + bf2f(e.y) * r.y + bf2f(e.z) * r.z + bf2f(e.w) * r.w;
  }
  #pragma unroll
  for (int off = 32; off > 0; off >>= 1) s += __shfl_xor(s, off);
  if (lane == 0) cinv[b * NP + m] = 1.0f / (s + 1e-9f);
}

// ---------- x_r via bf16 MFMA ----------
constexpr int LDA = 72;  // bf16 units per LDS row (64 + 8 pad)

__global__ __launch_bounds__(256) void k_xr_mfma(const float* __restrict__ H, float* __restrict__ U,
                                                 const ushort* __restrict__ E,
                                                 const float* __restrict__ rinv,
                                                 const float* __restrict__ cinv, int C) {
  int b = blockIdx.z, m0 = blockIdx.x * 128, c0 = blockIdx.y * 128;
  int tid = threadIdx.x, lane = tid & 63, w = tid >> 6;
  int wr = w >> 1, wc = w & 1;
  const float* Hb = H + (size_t)b * C * NP;
  float* Ub = U + (size_t)b * C * NP;
  const ushort* Eb = E + (size_t)b * NP * NP;
  const float* rb = rinv + b * NP;
  const float* cb = cinv + b * NP;
  __shared__ ushort Asm[128 * LDA];
  __shared__ ushort Bsm[128 * LDA];
  f32x4 acc[4][4];
  #pragma unroll
  for (int i = 0; i < 4; ++i)
    #pragma unroll
    for (int j = 0; j < 4; ++j) acc[i][j] = (f32x4)(0.0f);

  int row = tid >> 1, half = tid & 1;
  for (int n0 = 0; n0 < NP; n0 += 64) {
    __syncthreads();
    {   // A: rows=c (128), cols=n' (64), value H*rinv -> bf16
      const float* src = Hb + (size_t)(c0 + row) * NP + n0 + half * 32;
      const float* rsrc = rb + n0 + half * 32;
      unsigned* dst = (unsigned*)(Asm + row * LDA + half * 32);
      #pragma unroll
      for (int i = 0; i < 8; ++i) {
        float4 hv = *(const float4*)(src + i * 4);
        float4 rv = *(const float4*)(rsrc + i * 4);
        dst[i * 2 + 0] = pk2bf(hv.x * rv.x, hv.y * rv.y);
        dst[i * 2 + 1] = pk2bf(hv.z * rv.z, hv.w * rv.w);
      }
      // B: rows=m' (128), cols=n' (64), E already bf16 [m][n]
      const ushort* esrc = Eb + (size_t)(m0 + row) * NP + n0 + half * 32;
      uint4* bdst = (uint4*)(Bsm + row * LDA + half * 32);
      #pragma unroll
      for (int i = 0; i < 4; ++i) bdst[i] = *(const uint4*)(esrc + i * 8);
    }
    __syncthreads();
    #pragma unroll
    for (int kk = 0; kk < 64; kk += 32) {
      bf16x8 af[4], bfr[4];
      #pragma unroll
      for (int i = 0; i < 4; ++i) {
        af[i]  = *(const bf16x8*)(Asm + (wr * 64 + i * 16 + (lane & 15)) * LDA + kk + (lane >> 4) * 8);
        bfr[i] = *(const bf16x8*)(Bsm + (wc * 64 + i * 16 + (lane & 15)) * LDA + kk + (lane >> 4) * 8);
      }
      #pragma unroll
      for (int i = 0; i < 4; ++i)
        #pragma unroll
        for (int j = 0; j < 4; ++j)
          acc[i][j] = MFMA16(af[i], bfr[j], acc[i][j]);
    }
  }
  #pragma unroll
  for (int j = 0; j < 4; ++j) {
    int m = m0 + wc * 64 + j * 16 + (lane & 15);
    float cm = cb[m];
    #pragma unroll
    for (int i = 0; i < 4; ++i) {
      int c = c0 + wr * 64 + i * 16 + (lane >> 4) * 4;
      #pragma unroll
      for (int r = 0; r < 4; ++r) {
        size_t idx = (size_t)(c + r) * NP + m;
        Ub[idx] = Hb[idx] - cm * acc[i][j][r];
      }
    }
  }
}

// ---------- conv1x1 via bf16 MFMA ----------
__global__ __launch_bounds__(256) void k_gemm_mfma(const float* __restrict__ W,
                                                   const float* __restrict__ IN,
                                                   const float* __restrict__ bias,
                                                   float* __restrict__ OUT,
                                                   int Cin, int Cout) {
  int b = blockIdx.z, n0 = blockIdx.x * 128, o0 = blockIdx.y * 128;
  int tid = threadIdx.x, lane = tid & 63, w = tid >> 6;
  int wr = w >> 1, wc = w & 1;
  const float* Ib = IN + (size_t)b * Cin * NP;
  float* Ob = OUT + (size_t)b * Cout * NP;
  __shared__ ushort Asm[128 * LDA];
  __shared__ ushort Bsm[128 * LDA];
  f32x4 acc[4][4];
  #pragma unroll
  for (int i = 0; i < 4; ++i)
    #pragma unroll
    for (int j = 0; j < 4; ++j) acc[i][j] = (f32x4)(0.0f);

  int row = tid >> 1, half = tid & 1;
  int csub = tid & 63, q = tid >> 6;
  for (int cc0 = 0; cc0 < Cin; cc0 += 64) {
    __syncthreads();
    {   // A: rows=o (128), cols=c' (64) from W
      const float* src = W + (size_t)(o0 + row) * Cin + cc0 + half * 32;
      unsigned* dst = (unsigned*)(Asm + row * LDA + half * 32);
      #pragma unroll
      for (int i = 0; i < 8; ++i) {
        float4 v = *(const float4*)(src + i * 4);
        dst[i * 2 + 0] = pk2bf(v.x, v.y);
        dst[i * 2 + 1] = pk2bf(v.z, v.w);
      }
      // B: rows=n' (128), cols=c' (64) — transpose of IN[c][n]
      const float* isrc = Ib + (size_t)(cc0 + csub) * NP + n0 + q * 32;
      #pragma unroll
      for (int i = 0; i < 8; ++i) {
        float4 v = *(const float4*)(isrc + i * 4);
        ushort* bd = Bsm + (q * 32 + i * 4) * LDA + csub;
        bd[0]       = f2bf(v.x);
        bd[LDA]     = f2bf(v.y);
        bd[2 * LDA] = f2bf(v.z);
        bd[3 * LDA] = f2bf(v.w);
      }
    }
    __syncthreads();
    #pragma unroll
    for (int kk = 0; kk < 64; kk += 32) {
      bf16x8 af[4], bfr[4];
      #pragma unroll
      for (int i = 0; i < 4; ++i) {
        af[i]  = *(const bf16x8*)(Asm + (wr * 64 + i * 16 + (lane & 15)) * LDA + kk + (lane >> 4) * 8);
        bfr[i] = *(const bf16x8*)(Bsm + (wc * 64 + i * 16 + (lane & 15)) * LDA + kk + (lane >> 4) * 8);
      }
      #pragma unroll
      for (int i = 0; i < 4; ++i)
        #pragma unroll
        for (int j = 0; j < 4; ++j)
          acc[i][j] = MFMA16(af[i], bfr[j], acc[i][j]);
    }
  }
  #pragma unroll
  for (int i = 0; i < 4; ++i) {
    #pragma unroll
    for (int r = 0; r < 4; ++r) {
      int o = o0 + wr * 64 + i * 16 + (lane >> 4) * 4 + r;
      float bv = bias[o];
      #pragma unroll
      for (int j = 0; j < 4; ++j) {
        int n = n0 + wc * 64 + j * 16 + (lane & 15);
        Ob[(size_t)o * NP + n] = acc[i][j][r] + bv;
      }
    }
  }
}

// ---------- fp32 GEMM (conv1 only, Cin=3) ----------
__global__ __launch_bounds__(256) void k_gemm(const float* __restrict__ W,
                                              const float* __restrict__ IN,
                                              const float* __restrict__ bias,
                                              float* __restrict__ OUT,
                                              int Cin, int Cout) {
  int b = blockIdx.z;
  int n0 = blockIdx.x * 64;
  int o0 = blockIdx.y * 64;
  int tid = threadIdx.x;
  int tx = tid & 15, ty = tid >> 4;
  const float* Ib = IN + (size_t)b * Cin * NP;
  float* Ob = OUT + (size_t)b * Cout * NP;
  __shared__ float Wt[64][65];
  __shared__ float It[64][65];
  float acc[4][4] = {};
  for (int c0 = 0; c0 < Cin; c0 += 64) {
    __syncthreads();
    {
      int ci = tid & 63, ob4 = tid >> 6;
      bool cv = (c0 + ci) < Cin;
      #pragma unroll
      for (int k = 0; k < 16; ++k) {
        int oi = ob4 + (k << 2);
        Wt[ci][oi] = cv ? W[(size_t)(o0 + oi) * Cin + c0 + ci] : 0.f;
      }
      int ni = tid & 63, cb4 = tid >> 6;
      #pragma unroll
      for (int k = 0; k < 16; ++k) {
        int ci2 = cb4 + (k << 2);
        It[ci2][ni] = (c0 + ci2) < Cin ? Ib[(size_t)(c0 + ci2) * NP + n0 + ni] : 0.f;
      }
    }
    __syncthreads();
    #pragma unroll 4
    for (int ci = 0; ci < 64; ++ci) {
      float a0 = Wt[ci][ty * 4 + 0], a1 = Wt[ci][ty * 4 + 1], a2 = Wt[ci][ty * 4 + 2], a3 = Wt[ci][ty * 4 + 3];
      float b0 = It[ci][tx * 4 + 0], b1 = It[ci][tx * 4 + 1], b2 = It[ci][tx * 4 + 2], b3 = It[ci][tx * 4 + 3];
      acc[0][0] += a0 * b0; acc[0][1] += a0 * b1; acc[0][2] += a0 * b2; acc[0][3] += a0 * b3;
      acc[1][0] += a1 * b0; acc[1][1] += a1 * b1; acc[1][2] += a1 * b2; acc[1][3] += a1 * b3;
      acc[2][0] += a2 * b0; acc[2][1] += a2 * b1; acc[2][2] += a2 * b2; acc[2][3] += a2 * b3;
      acc[3][0] += a3 * b0; acc[3][1] += a3 * b1; acc[3][2] += a3 * b2; acc[3][3] += a3 * b3;
    }
  }
  #pragma unroll
  for (int i = 0; i < 4; ++i) {
    int o = o0 + ty * 4 + i;
    float bv = bias[o];
    #pragma unroll
    for (int j = 0; j < 4; ++j) {
      int n = n0 + tx * 4 + j;
      Ob[(size_t)o * NP + n] = acc[i][j] + bv;
    }
  }
}

// ---------- BN stats per channel over (B, N) ----------
__global__ __launch_bounds__(256) void k_bnstats(const float* __restrict__ T,
                                                 float* __restrict__ mean,
                                                 float* __restrict__ istd, int C) {
  int c = blockIdx.x;
  int tid = threadIdx.x;
  float s = 0.f, s2 = 0.f;
  for (int b = 0; b < NB; ++b) {
    const float* p = T + ((size_t)b * C + c) * NP;
    for (int n = tid * 4; n < NP; n += 1024) {
      float4 v = *(const float4*)(p + n);
      s += (v.x + v.y) + (v.z + v.w);
      s2 += (v.x * v.x + v.y * v.y) + (v.z * v.z + v.w * v.w);
    }
  }
  __shared__ float rs[256], rs2[256];
  rs[tid] = s; rs2[tid] = s2;
  __syncthreads();
  for (int off = 128; off > 0; off >>= 1) {
    if (tid < off) { rs[tid] += rs[tid + off]; rs2[tid] += rs2[tid + off]; }
    __syncthreads();
  }
  if (tid == 0) {
    float m = rs[0] / (float)(NB * NP);
    float var = rs2[0] / (float)(NB * NP) - m * m;
    mean[c] = m;
    istd[c] = rsqrtf(var + 1e-5f);
  }
}

// ---------- BN apply (+optional relu, +optional accumulate), float4 ----------
__global__ __launch_bounds__(256) void k_bnapply(const float4* __restrict__ T, float4* __restrict__ H,
                                                 const float* __restrict__ mean,
                                                 const float* __restrict__ istd,
                                                 int C, int relu, int acc) {
  size_t i = (size_t)blockIdx.x * 256 + threadIdx.x;   // float4 index; NP/4=512 per row
  int c = (int)((i >> 9) % C);
  float m = mean[c], is = istd[c];
  float4 v = T[i];
  v.x = (v.x - m) * is; v.y = (v.y - m) * is; v.z = (v.z - m) * is; v.w = (v.w - m) * is;
  if (relu) {
    v.x = fmaxf(v.x, 0.f); v.y = fmaxf(v.y, 0.f); v.z = fmaxf(v.z, 0.f); v.w = fmaxf(v.w, 0.f);
  }
  if (acc) {
    float4 h = H[i];
    v.x += h.x; v.y += h.y; v.z += h.z; v.w += h.w;
  }
  H[i] = v;
}

// ---------- global max pool over N ----------
__global__ __launch_bounds__(64) void k_maxpool(const float* __restrict__ H, float* __restrict__ g) {
  int bf = blockIdx.x;
  const float* p = H + (size_t)bf * NP;
  int lane = threadIdx.x;
  float mx = -FLT_MAX;
  for (int n = lane; n < NP; n += 64) mx = fmaxf(mx, p[n]);
  #pragma unroll
  for (int off = 32; off > 0; off >>= 1) mx = fmaxf(mx, __shfl_xor(mx, off));
  if (lane == 0) g[bf] = mx;
}

// ---------- MLP head ----------
__global__ __launch_bounds__(256) void k_head(const float* __restrict__ g,
    const float* __restrict__ f1mw, const float* __restrict__ f1mb,
    const float* __restrict__ f2mw, const float* __restrict__ f2mb,
    const float* __restrict__ f3mw, const float* __restrict__ f3mb,
    const float* __restrict__ f1vw, const float* __restrict__ f1vb,
    const float* __restrict__ f2vw, const float* __restrict__ f2vb,
    const float* __restrict__ f3vw, const float* __restrict__ f3vb,
    float* __restrict__ out) {
  bool vpath = (blockIdx.x == 1);
  const float* w1 = vpath ? f1vw : f1mw;
  const float* c1 = vpath ? f1vb : f1mb;
  const float* w2 = vpath ? f2vw : f2mw;
  const float* c2 = vpath ? f2vb : f2mb;
  __shared__ float gg[NB * 512];
  __shared__ float a1[NB * 256];
  __shared__ float a2[NB * 128];
  __shared__ float zz[NB * 128];
  __shared__ float nrm[NB];
  int t = threadIdx.x;
  for (int i = t; i < NB * 512; i += 256) gg[i] = g[i];
  __syncthreads();
  float o[NB];
  {
    #pragma unroll
    for (int b = 0; b < NB; ++b) o[b] = c1[t];
    const float* wr = w1 + (size_t)t * 512;
    for (int j = 0; j < 512; ++j) {
      float w = wr[j];
      #pragma unroll
      for (int b = 0; b < NB; ++b) o[b] += gg[b * 512 + j] * w;
    }
    float mean = 0.f;
    #pragma unroll
    for (int b = 0; b < NB; ++b) mean += o[b];
    mean *= (1.0f / NB);
    float var = 0.f;
    #pragma unroll
    for (int b = 0; b < NB; ++b) { float d = o[b] - mean; var += d * d; }
    var *= (1.0f / NB);
    float is = rsqrtf(var + 1e-5f);
    #pragma unroll
    for (int b = 0; b < NB; ++b) a1[b * 256 + t] = fmaxf((o[b] - mean) * is, 0.f);
  }
  __syncthreads();
  if (t < 128) {
    #pragma unroll
    for (int b = 0; b < NB; ++b) o[b] = c2[t];
    const float* wr = w2 + (size_t)t * 256;
    for (int j = 0; j < 256; ++j) {
      float w = wr[j];
      #pragma unroll
      for (int b = 0; b < NB; ++b) o[b] += a1[b * 256 + j] * w;
    }
    float mean = 0.f;
    #pragma unroll
    for (int b = 0; b < NB; ++b) mean += o[b];
    mean *= (1.0f / NB);
    float var = 0.f;
    #pragma unroll
    for (int b = 0; b < NB; ++b) { float d = o[b] - mean; var += d * d; }
    var *= (1.0f / NB);
    float is = rsqrtf(var + 1e-5f);
    #pragma unroll
    for (int b = 0; b < NB; ++b) a2[b * 128 + t] = fmaxf((o[b] - mean) * is, 0.f);
  }
  __syncthreads();
  if (!vpath) {
    if (t < 128) {
      const float* wr = f3mw + (size_t)t * 128;
      for (int b = 0; b < NB; ++b) {
        float s = f3mb[t];
        for (int j = 0; j < 128; ++j) s += a2[b * 128 + j] * wr[j];
        zz[b * 128 + t] = s;
      }
    }
    __syncthreads();
    if (t < NB) {
      float s = 0.f;
      for (int j = 0; j < 128; ++j) { float v = zz[t * 128 + j]; s += v * v; }
      nrm[t] = sqrtf(s);
    }
    __syncthreads();
    if (t < 128) {
      for (int b = 0; b < NB; ++b) out[b * 128 + t] = zz[b * 128 + t] / nrm[b];
    }
  } else {
    if (t < NB) {
      float s = f3vb[0];
      for (int j = 0; j < 128; ++j) s += a2[t * 128 + j] * f3vw[j];
      float sp = (s > 20.f) ? s : log1pf(expf(s));
      out[NB * 128 + t] = sp + 1.0f;
    }
  }
}

extern "C" void kernel_launch(void* const* d_in, const int* in_sizes, int n_in,
                              void* d_out, int out_size, void* d_ws, size_t ws_size,
                              hipStream_t stream) {
  const float* x  = (const float*)d_in[0];
  const float* w1 = (const float*)d_in[1];
  const float* b1 = (const float*)d_in[2];
  const float* w2 = (const float*)d_in[3];
  const float* b2 = (const float*)d_in[4];
  const float* w3 = (const float*)d_in[5];
  const float* b3 = (const float*)d_in[6];
  const float* w4 = (const float*)d_in[7];
  const float* b4 = (const float*)d_in[8];
  const float* a_wqk[4] = {(const float*)d_in[9],  (const float*)d_in[12], (const float*)d_in[15], (const float*)d_in[18]};
  const float* a_wt[4]  = {(const float*)d_in[10], (const float*)d_in[13], (const float*)d_in[16], (const float*)d_in[19]};
  const float* a_bt[4]  = {(const float*)d_in[11], (const float*)d_in[14], (const float*)d_in[17], (const float*)d_in[20]};
  int a_D[4] = {in_sizes[9], in_sizes[12], in_sizes[15], in_sizes[18]};
  const float* f1mw = (const float*)d_in[21]; const float* f1mb = (const float*)d_in[22];
  const float* f2mw = (const float*)d_in[23]; const float* f2mb = (const float*)d_in[24];
  const float* f3mw = (const float*)d_in[25]; const float* f3mb = (const float*)d_in[26];
  const float* f1vw = (const float*)d_in[27]; const float* f1vb = (const float*)d_in[28];
  const float* f2vw = (const float*)d_in[29]; const float* f2vb = (const float*)d_in[30];
  const float* f3vw = (const float*)d_in[31]; const float* f3vb = (const float*)d_in[32];
  float* out = (float*)d_out;

  float* ws = (float*)d_ws;
  float* xn     = ws; ws += (size_t)NB * NP * 3;
  float* dens   = ws; ws += NB * NP;
  float* maxinv = ws; ws += 16;
  float* Ls     = ws; ws += 16;
  float* rinv   = ws; ws += NB * NP;
  float* cinv   = ws; ws += NB * NP;
  float* bn_m   = ws; ws += 512;
  float* bn_is  = ws; ws += 512;
  float* g      = ws; ws += NB * 512;
  float* Hb     = ws; ws += (size_t)NB * 512 * NP;
  float* Ub     = ws; ws += (size_t)NB * 512 * NP;
  float* Tb     = ws; ws += (size_t)NB * 512 * NP;
  ushort* E     = (ushort*)Tb;   // E (64MB bf16) aliases Tb (dead when Tb is written)

  k_prep<<<NB * NP / 256, 256, 0, stream>>>(x, xn, Ub);   // Ub temporarily holds x^T [B,3,N]
  k_zero1<<<1, 64, 0, stream>>>(maxinv);
  k_density<<<NB * NP / 8, 512, 0, stream>>>(xn, dens, (int*)maxinv);
  k_scale<<<NB * NP / 256, 256, 0, stream>>>(dens, maxinv);

  auto conv = [&](const float* W, const float* bias, const float* IN, int Cin, int Cout, bool relu) {
    if (Cin < 64)
      k_gemm<<<dim3(NP / 64, Cout / 64, NB), 256, 0, stream>>>(W, IN, bias, Tb, Cin, Cout);
    else
      k_gemm_mfma<<<dim3(NP / 128, Cout / 128, NB), 256, 0, stream>>>(W, IN, bias, Tb, Cin, Cout);
    k_bnstats<<<Cout, 256, 0, stream>>>(Tb, bn_m, bn_is, Cout);
    k_bnapply<<<(int)(((size_t)NB * Cout * NP) / 1024), 256, 0, stream>>>((const float4*)Tb, (float4*)Hb, bn_m, bn_is, Cout, relu ? 1 : 0, 0);
  };
  auto attn = [&](int li, int C) {
    k_attn_prep<<<1, 128, 0, stream>>>(a_wqk[li], a_D[li], Ls);
    k_expmat<<<dim3(NB, NP / 4), 256, 0, stream>>>(dens, Ls, E, rinv);
    k_csum<<<dim3(NB, NP / 4), 256, 0, stream>>>(E, rinv, cinv);
    k_xr_mfma<<<dim3(NP / 128, C / 128, NB), 256, 0, stream>>>(Hb, Ub, E, rinv, cinv, C);
    k_gemm_mfma<<<dim3(NP / 128, C / 128, NB), 256, 0, stream>>>(a_wt[li], Ub, a_bt[li], Tb, C, C);
    k_bnstats<<<C, 256, 0, stream>>>(Tb, bn_m, bn_is, C);
    k_bnapply<<<(int)(((size_t)NB * C * NP) / 1024), 256, 0, stream>>>((const float4*)Tb, (float4*)Hb, bn_m, bn_is, C, 1, 1);
  };

  conv(w1, b1, Ub, 3, 128, true);
  attn(0, 128);
  conv(w2, b2, Hb, 128, 128, true);
  attn(1, 128);
  conv(w3, b3, Hb, 128, 256, true);
  attn(2, 256);
  conv(w4, b4, Hb, 256, 512, false);
  attn(3, 512);

  k_maxpool<<<NB * 512, 64, 0, stream>>>(Hb, g);
  k_head<<<2, 256, 0, stream>>>(g, f1mw, f1mb, f2mw, f2mb, f3mw, f3mb,
                                f1vw, f1vb, f2vw, f2vb, f3vw, f3vb, out);
}

// Round 7
// 883.577 us; speedup vs baseline: 1.3811x; 1.1438x over previous
//
#include <hip/hip_runtime.h>
#include <cfloat>
#include <cmath>

constexpr int NB = 8;
constexpr int NP = 2048;
constexpr float LOG2E_F = 1.4426950408889634f;

typedef __attribute__((ext_vector_type(4))) float f32x4;
typedef __attribute__((ext_vector_type(8))) short bf16x8;
#define MFMA16(a, b, c) __builtin_amdgcn_mfma_f32_16x16x32_bf16(a, b, c, 0, 0, 0)

__device__ inline ushort f2bf(float f) {   // round-to-nearest-even f32 -> bf16
  union { float f; unsigned u; } v; v.f = f;
  unsigned r = v.u + 0x7FFFu + ((v.u >> 16) & 1u);
  return (ushort)(r >> 16);
}
__device__ inline unsigned pk2bf(float a, float b) {
  return (unsigned)f2bf(a) | ((unsigned)f2bf(b) << 16);
}
__device__ inline float bf2f(ushort u) {
  union { unsigned u; float f; } v; v.u = ((unsigned)u) << 16; return v.f;
}

// Per-32-lane-half sum: after row_shr 1/2/4/8 + row_bcast:15, lane31 holds
// sum(lanes 0..31), lane63 holds sum(lanes 32..63).
__device__ inline int dpp_half_sum_i32(int c) {
  c += __builtin_amdgcn_update_dpp(0, c, 0x111, 0xf, 0xf, true);  // row_shr:1
  c += __builtin_amdgcn_update_dpp(0, c, 0x112, 0xf, 0xf, true);  // row_shr:2
  c += __builtin_amdgcn_update_dpp(0, c, 0x114, 0xf, 0xf, true);  // row_shr:4
  c += __builtin_amdgcn_update_dpp(0, c, 0x118, 0xf, 0xf, true);  // row_shr:8
  c += __builtin_amdgcn_update_dpp(0, c, 0x142, 0xf, 0xf, true);  // row_bcast:15
  return c;
}

// ---------- prep: normalize x -> xn ; transpose x -> xt [B,3,N] ----------
__global__ void k_prep(const float* __restrict__ x, float* __restrict__ xn, float* __restrict__ xt) {
  int i = blockIdx.x * blockDim.x + threadIdx.x;
  if (i >= NB * NP) return;
  int b = i >> 11, n = i & (NP - 1);
  float a0 = x[i * 3 + 0], a1 = x[i * 3 + 1], a2 = x[i * 3 + 2];
  float rn = rsqrtf(a0 * a0 + a1 * a1 + a2 * a2);
  xn[i * 3 + 0] = a0 * rn; xn[i * 3 + 1] = a1 * rn; xn[i * 3 + 2] = a2 * rn;
  float* xb = xt + (size_t)b * 3 * NP;
  xb[0 * NP + n] = a0; xb[1 * NP + n] = a1; xb[2 * NP + n] = a2;
}

__global__ void k_zero1(float* p) { if (threadIdx.x == 0) p[0] = 0.f; }

// ---------- density: 2 rows per wave, branchless binary search ----------
// Block = 512 threads = 8 waves = 16 rows (one batch). Lanes 0-31 = row A,
// lanes 32-63 = row B; 64 values/lane. No barriers after staging; the only
// cross-lane ops per iteration are 5 DPP adds + 1 ds_bpermute.
__global__ __launch_bounds__(512) void k_density(const float* __restrict__ xn,
                                                 float* __restrict__ inv,
                                                 int* __restrict__ maxinv) {
  __shared__ float sx[NP], sy[NP], sz[NP];
  int t = threadIdx.x;
  int w = t >> 6, lane = t & 63, half = lane >> 5, sl = lane & 31;
  int row0 = blockIdx.x * 16;
  int b = row0 >> 11;                       // 128 blocks per batch
  const float4* xb4 = (const float4*)(xn + (size_t)b * NP * 3);
  {  // thread t stages points 4t..4t+3 (3 coalesced float4 loads)
    float4 a = xb4[t * 3 + 0], c4 = xb4[t * 3 + 1], e4 = xb4[t * 3 + 2];
    int p = t * 4;
    sx[p + 0] = a.x;  sy[p + 0] = a.y;  sz[p + 0] = a.z;
    sx[p + 1] = a.w;  sy[p + 1] = c4.x; sz[p + 1] = c4.y;
    sx[p + 2] = c4.z; sy[p + 2] = c4.w; sz[p + 2] = e4.x;
    sx[p + 3] = e4.y; sy[p + 3] = e4.z; sz[p + 3] = e4.w;
  }
  __syncthreads();
  int row = row0 + w * 2 + half;
  int n = row & (NP - 1);
  float px = sx[n], py = sy[n], pz = sz[n];
  float d[64];
  float mn = FLT_MAX, mx = -FLT_MAX;
  #pragma unroll
  for (int k = 0; k < 64; ++k) {
    int m = sl + (k << 5);                  // 32 consecutive addrs per half
    float v = 1.0f - (px * sx[m] + py * sy[m] + pz * sz[m]);
    d[k] = v;
    mn = fminf(mn, v); mx = fmaxf(mx, v);
  }
  // per-half bounds: mn = row min; mx = min over lanes of per-lane max
  // (each lane has 64 values <= its max => >=64 values <= min-of-maxes)
  #pragma unroll
  for (int off = 16; off; off >>= 1) {      // xor offsets 1..16 stay in half
    mn = fminf(mn, __shfl_xor(mn, off));
    mx = fminf(mx, __shfl_xor(mx, off));
  }
  float lo = mn, hi = mx + 1e-6f;
  int baddr = (half ? 63 : 31) << 2;        // bpermute source lane
  for (int it = 0; it < 18; ++it) {
    float tt = 0.5f * (lo + hi);
    int c = 0;
    #pragma unroll
    for (int k = 0; k < 64; ++k) c += (d[k] < tt) ? 1 : 0;
    c = dpp_half_sum_i32(c);
    int ct = __builtin_amdgcn_ds_bpermute(baddr, c);   // half-total to all lanes
    bool le = ct <= 32;
    lo = le ? tt : lo;                      // branchless update
    hi = le ? hi : tt;
  }
  float s = 0.f; int c = 0;
  #pragma unroll
  for (int k = 0; k < 64; ++k) {
    bool p = d[k] < lo;
    s += p ? d[k] : 0.f;
    c += p ? 1 : 0;
  }
  c = dpp_half_sum_i32(c);
  int ctot = __builtin_amdgcn_ds_bpermute(baddr, c);
  #pragma unroll
  for (int off = 16; off; off >>= 1) s += __shfl_xor(s, off);
  float sum = s + (float)(32 - ctot) * lo;  // pad remaining picks at threshold
  if (sl == 0) {
    float iv = 32.0f / sum;
    inv[row] = iv;
    atomicMax(maxinv, __float_as_int(iv));
  }
}

// ---------- attn prep: Ls = (sum wqk^2) * log2(e) / max(inv)^2 ----------
__global__ __launch_bounds__(128) void k_attn_prep(const float* __restrict__ wqk, int D,
                                                   const float* __restrict__ maxinv,
                                                   float* __restrict__ Ls) {
  __shared__ float part[128];
  int t = threadIdx.x;
  float v = (t < D) ? wqk[t] * wqk[t] : 0.f;
  part[t] = v;
  __syncthreads();
  for (int off = 64; off > 0; off >>= 1) {
    if (t < off) part[t] += part[t + off];
    __syncthreads();
  }
  if (t == 0) {
    float mx = maxinv[0];
    Ls[0] = part[0] * LOG2E_F / (mx * mx);
  }
}

// ---------- E[b][m][n] = exp2(Ls*dm*dn) (bf16), rinv[b][m] = 1/rowsum ----------
__global__ __launch_bounds__(256) void k_expmat(const float* __restrict__ dens,
                                                const float* __restrict__ Lsp,
                                                ushort* __restrict__ E,
                                                float* __restrict__ rinv) {
  int b = blockIdx.x;
  int m = blockIdx.y * 4 + (threadIdx.x >> 6);
  int lane = threadIdx.x & 63;
  const float* db = dens + b * NP;
  float f = Lsp[0] * db[m];
  ushort* Em = E + ((size_t)b * NP + m) * NP;
  float s = 0.f;
  for (int it = 0; it < 8; ++it) {
    int n = it * 256 + lane * 4;
    float4 d = *(const float4*)(db + n);
    float e0 = exp2f(f * d.x), e1 = exp2f(f * d.y), e2 = exp2f(f * d.z), e3 = exp2f(f * d.w);
    s += (e0 + e1) + (e2 + e3);
    ushort4 o; o.x = f2bf(e0); o.y = f2bf(e1); o.z = f2bf(e2); o.w = f2bf(e3);
    *(ushort4*)(Em + n) = o;
  }
  #pragma unroll
  for (int off = 32; off > 0; off >>= 1) s += __shfl_xor(s, off);
  if (lane == 0) rinv[b * NP + m] = 1.0f / s;
}

// ---------- cinv[b][m] = 1/(1e-9 + sum_n E[m][n]*rinv[n])  (E symmetric) ----------
__global__ __launch_bounds__(256) void k_csum(const ushort* __restrict__ E,
                                              const float* __restrict__ rinv,
                                              float* __restrict__ cinv) {
  int b = blockIdx.x;
  int m = blockIdx.y * 4 + (threadIdx.x >> 6);
  int lane = threadIdx.x & 63;
  const ushort* Em = E + ((size_t)b * NP + m) * NP;
  const float* rb = rinv + b * NP;
  float s = 0.f;
  for (int it = 0; it < 8; ++it) {
    int n = it * 256 + lane * 4;
    ushort4 e = *(const ushort4*)(Em + n);
    float4 r = *(const float4*)(rb + n);
    s += bf2f(e.x) * r.x + bf2f(e.y) * r.y + bf2f(e.z) * r.z + bf2f(e.w) * r.w;
  }
  #pragma unroll
  for (int off = 32; off > 0; off >>= 1) s += __shfl_xor(s, off);
  if (lane == 0) cinv[b * NP + m] = 1.0f / (s + 1e-9f);
}

// ---------- x_r via bf16 MFMA ----------
constexpr int LDA = 72;  // bf16 units per LDS row (64 + 8 pad)

__global__ __launch_bounds__(256) void k_xr_mfma(const float* __restrict__ H, float* __restrict__ U,
                                                 const ushort* __restrict__ E,
                                                 const float* __restrict__ rinv,
                                                 const float* __restrict__ cinv, int C) {
  int b = blockIdx.z, m0 = blockIdx.x * 128, c0 = blockIdx.y * 128;
  int tid = threadIdx.x, lane = tid & 63, w = tid >> 6;
  int wr = w >> 1, wc = w & 1;
  const float* Hb = H + (size_t)b * C * NP;
  float* Ub = U + (size_t)b * C * NP;
  const ushort* Eb = E + (size_t)b * NP * NP;
  const float* rb = rinv + b * NP;
  const float* cb = cinv + b * NP;
  __shared__ ushort Asm[128 * LDA];
  __shared__ ushort Bsm[128 * LDA];
  f32x4 acc[4][4];
  #pragma unroll
  for (int i = 0; i < 4; ++i)
    #pragma unroll
    for (int j = 0; j < 4; ++j) acc[i][j] = (f32x4)(0.0f);

  int row = tid >> 1, half = tid & 1;
  for (int n0 = 0; n0 < NP; n0 += 64) {
    __syncthreads();
    {   // A: rows=c (128), cols=n' (64), value H*rinv -> bf16
      const float* src = Hb + (size_t)(c0 + row) * NP + n0 + half * 32;
      const float* rsrc = rb + n0 + half * 32;
      unsigned* dst = (unsigned*)(Asm + row * LDA + half * 32);
      #pragma unroll
      for (int i = 0; i < 8; ++i) {
        float4 hv = *(const float4*)(src + i * 4);
        float4 rv = *(const float4*)(rsrc + i * 4);
        dst[i * 2 + 0] = pk2bf(hv.x * rv.x, hv.y * rv.y);
        dst[i * 2 + 1] = pk2bf(hv.z * rv.z, hv.w * rv.w);
      }
      // B: rows=m' (128), cols=n' (64), E already bf16 [m][n]
      const ushort* esrc = Eb + (size_t)(m0 + row) * NP + n0 + half * 32;
      uint4* bdst = (uint4*)(Bsm + row * LDA + half * 32);
      #pragma unroll
      for (int i = 0; i < 4; ++i) bdst[i] = *(const uint4*)(esrc + i * 8);
    }
    __syncthreads();
    #pragma unroll
    for (int kk = 0; kk < 64; kk += 32) {
      bf16x8 af[4], bfr[4];
      #pragma unroll
      for (int i = 0; i < 4; ++i) {
        af[i]  = *(const bf16x8*)(Asm + (wr * 64 + i * 16 + (lane & 15)) * LDA + kk + (lane >> 4) * 8);
        bfr[i] = *(const bf16x8*)(Bsm + (wc * 64 + i * 16 + (lane & 15)) * LDA + kk + (lane >> 4) * 8);
      }
      #pragma unroll
      for (int i = 0; i < 4; ++i)
        #pragma unroll
        for (int j = 0; j < 4; ++j)
          acc[i][j] = MFMA16(af[i], bfr[j], acc[i][j]);
    }
  }
  #pragma unroll
  for (int j = 0; j < 4; ++j) {
    int m = m0 + wc * 64 + j * 16 + (lane & 15);
    float cm = cb[m];
    #pragma unroll
    for (int i = 0; i < 4; ++i) {
      int c = c0 + wr * 64 + i * 16 + (lane >> 4) * 4;
      #pragma unroll
      for (int r = 0; r < 4; ++r) {
        size_t idx = (size_t)(c + r) * NP + m;
        Ub[idx] = Hb[idx] - cm * acc[i][j][r];
      }
    }
  }
}

// ---------- conv1x1 via bf16 MFMA ----------
__global__ __launch_bounds__(256) void k_gemm_mfma(const float* __restrict__ W,
                                                   const float* __restrict__ IN,
                                                   const float* __restrict__ bias,
                                                   float* __restrict__ OUT,
                                                   int Cin, int Cout) {
  int b = blockIdx.z, n0 = blockIdx.x * 128, o0 = blockIdx.y * 128;
  int tid = threadIdx.x, lane = tid & 63, w = tid >> 6;
  int wr = w >> 1, wc = w & 1;
  const float* Ib = IN + (size_t)b * Cin * NP;
  float* Ob = OUT + (size_t)b * Cout * NP;
  __shared__ ushort Asm[128 * LDA];
  __shared__ ushort Bsm[128 * LDA];
  f32x4 acc[4][4];
  #pragma unroll
  for (int i = 0; i < 4; ++i)
    #pragma unroll
    for (int j = 0; j < 4; ++j) acc[i][j] = (f32x4)(0.0f);

  int row = tid >> 1, half = tid & 1;
  int csub = tid & 63, q = tid >> 6;
  for (int cc0 = 0; cc0 < Cin; cc0 += 64) {
    __syncthreads();
    {   // A: rows=o (128), cols=c' (64) from W
      const float* src = W + (size_t)(o0 + row) * Cin + cc0 + half * 32;
      unsigned* dst = (unsigned*)(Asm + row * LDA + half * 32);
      #pragma unroll
      for (int i = 0; i < 8; ++i) {
        float4 v = *(const float4*)(src + i * 4);
        dst[i * 2 + 0] = pk2bf(v.x, v.y);
        dst[i * 2 + 1] = pk2bf(v.z, v.w);
      }
      // B: rows=n' (128), cols=c' (64) — transpose of IN[c][n]
      const float* isrc = Ib + (size_t)(cc0 + csub) * NP + n0 + q * 32;
      #pragma unroll
      for (int i = 0; i < 8; ++i) {
        float4 v = *(const float4*)(isrc + i * 4);
        ushort* bd = Bsm + (q * 32 + i * 4) * LDA + csub;
        bd[0]       = f2bf(v.x);
        bd[LDA]     = f2bf(v.y);
        bd[2 * LDA] = f2bf(v.z);
        bd[3 * LDA] = f2bf(v.w);
      }
    }
    __syncthreads();
    #pragma unroll
    for (int kk = 0; kk < 64; kk += 32) {
      bf16x8 af[4], bfr[4];
      #pragma unroll
      for (int i = 0; i < 4; ++i) {
        af[i]  = *(const bf16x8*)(Asm + (wr * 64 + i * 16 + (lane & 15)) * LDA + kk + (lane >> 4) * 8);
        bfr[i] = *(const bf16x8*)(Bsm + (wc * 64 + i * 16 + (lane & 15)) * LDA + kk + (lane >> 4) * 8);
      }
      #pragma unroll
      for (int i = 0; i < 4; ++i)
        #pragma unroll
        for (int j = 0; j < 4; ++j)
          acc[i][j] = MFMA16(af[i], bfr[j], acc[i][j]);
    }
  }
  #pragma unroll
  for (int i = 0; i < 4; ++i) {
    #pragma unroll
    for (int r = 0; r < 4; ++r) {
      int o = o0 + wr * 64 + i * 16 + (lane >> 4) * 4 + r;
      float bv = bias[o];
      #pragma unroll
      for (int j = 0; j < 4; ++j) {
        int n = n0 + wc * 64 + j * 16 + (lane & 15);
        Ob[(size_t)o * NP + n] = acc[i][j][r] + bv;
      }
    }
  }
}

// ---------- fp32 GEMM (conv1 only, Cin=3) ----------
__global__ __launch_bounds__(256) void k_gemm(const float* __restrict__ W,
                                              const float* __restrict__ IN,
                                              const float* __restrict__ bias,
                                              float* __restrict__ OUT,
                                              int Cin, int Cout) {
  int b = blockIdx.z;
  int n0 = blockIdx.x * 64;
  int o0 = blockIdx.y * 64;
  int tid = threadIdx.x;
  int tx = tid & 15, ty = tid >> 4;
  const float* Ib = IN + (size_t)b * Cin * NP;
  float* Ob = OUT + (size_t)b * Cout * NP;
  __shared__ float Wt[64][65];
  __shared__ float It[64][65];
  float acc[4][4] = {};
  for (int c0 = 0; c0 < Cin; c0 += 64) {
    __syncthreads();
    {
      int ci = tid & 63, ob4 = tid >> 6;
      bool cv = (c0 + ci) < Cin;
      #pragma unroll
      for (int k = 0; k < 16; ++k) {
        int oi = ob4 + (k << 2);
        Wt[ci][oi] = cv ? W[(size_t)(o0 + oi) * Cin + c0 + ci] : 0.f;
      }
      int ni = tid & 63, cb4 = tid >> 6;
      #pragma unroll
      for (int k = 0; k < 16; ++k) {
        int ci2 = cb4 + (k << 2);
        It[ci2][ni] = (c0 + ci2) < Cin ? Ib[(size_t)(c0 + ci2) * NP + n0 + ni] : 0.f;
      }
    }
    __syncthreads();
    #pragma unroll 4
    for (int ci = 0; ci < 64; ++ci) {
      float a0 = Wt[ci][ty * 4 + 0], a1 = Wt[ci][ty * 4 + 1], a2 = Wt[ci][ty * 4 + 2], a3 = Wt[ci][ty * 4 + 3];
      float b0 = It[ci][tx * 4 + 0], b1 = It[ci][tx * 4 + 1], b2 = It[ci][tx * 4 + 2], b3 = It[ci][tx * 4 + 3];
      acc[0][0] += a0 * b0; acc[0][1] += a0 * b1; acc[0][2] += a0 * b2; acc[0][3] += a0 * b3;
      acc[1][0] += a1 * b0; acc[1][1] += a1 * b1; acc[1][2] += a1 * b2; acc[1][3] += a1 * b3;
      acc[2][0] += a2 * b0; acc[2][1] += a2 * b1; acc[2][2] += a2 * b2; acc[2][3] += a2 * b3;
      acc[3][0] += a3 * b0; acc[3][1] += a3 * b1; acc[3][2] += a3 * b2; acc[3][3] += a3 * b3;
    }
  }
  #pragma unroll
  for (int i = 0; i < 4; ++i) {
    int o = o0 + ty * 4 + i;
    float bv = bias[o];
    #pragma unroll
    for (int j = 0; j < 4; ++j) {
      int n = n0 + tx * 4 + j;
      Ob[(size_t)o * NP + n] = acc[i][j] + bv;
    }
  }
}

// ---------- fused BN: stats + apply, values held in registers ----------
// One block per channel; 256 threads x 16 float4 = 16384 values.
__global__ __launch_bounds__(256) void k_bn(const float* __restrict__ T, float* __restrict__ H,
                                            int C, int relu, int acc) {
  int c = blockIdx.x, t = threadIdx.x, w = t >> 6, lane = t & 63;
  float4 v[16];
  float s = 0.f, s2 = 0.f;
  #pragma unroll
  for (int b = 0; b < NB; ++b) {
    const float4* p = (const float4*)(T + ((size_t)b * C + c) * NP);
    #pragma unroll
    for (int i = 0; i < 2; ++i) {
      float4 x = p[t + i * 256];
      v[b * 2 + i] = x;
      s += (x.x + x.y) + (x.z + x.w);
      s2 += (x.x * x.x + x.y * x.y) + (x.z * x.z + x.w * x.w);
    }
  }
  #pragma unroll
  for (int off = 32; off; off >>= 1) { s += __shfl_xor(s, off); s2 += __shfl_xor(s2, off); }
  __shared__ float ps[4], ps2[4];
  if (lane == 0) { ps[w] = s; ps2[w] = s2; }
  __syncthreads();
  float ts = (ps[0] + ps[1]) + (ps[2] + ps[3]);
  float ts2 = (ps2[0] + ps2[1]) + (ps2[2] + ps2[3]);
  float m = ts * (1.0f / (NB * NP));
  float var = ts2 * (1.0f / (NB * NP)) - m * m;
  float is = rsqrtf(var + 1e-5f);
  #pragma unroll
  for (int b = 0; b < NB; ++b) {
    float4* hp = (float4*)(H + ((size_t)b * C + c) * NP);
    #pragma unroll
    for (int i = 0; i < 2; ++i) {
      float4 x = v[b * 2 + i];
      x.x = (x.x - m) * is; x.y = (x.y - m) * is; x.z = (x.z - m) * is; x.w = (x.w - m) * is;
      if (relu) {
        x.x = fmaxf(x.x, 0.f); x.y = fmaxf(x.y, 0.f); x.z = fmaxf(x.z, 0.f); x.w = fmaxf(x.w, 0.f);
      }
      if (acc) {
        float4 h = hp[t + i * 256];
        x.x += h.x; x.y += h.y; x.z += h.z; x.w += h.w;
      }
      hp[t + i * 256] = x;
    }
  }
}

// ---------- global max pool over N ----------
__global__ __launch_bounds__(64) void k_maxpool(const float* __restrict__ H, float* __restrict__ g) {
  int bf = blockIdx.x;
  const float* p = H + (size_t)bf * NP;
  int lane = threadIdx.x;
  float mx = -FLT_MAX;
  for (int n = lane; n < NP; n += 64) mx = fmaxf(mx, p[n]);
  #pragma unroll
  for (int off = 32; off > 0; off >>= 1) mx = fmaxf(mx, __shfl_xor(mx, off));
  if (lane == 0) g[bf] = mx;
}

// ---------- MLP head ----------
__global__ __launch_bounds__(256) void k_head(const float* __restrict__ g,
    const float* __restrict__ f1mw, const float* __restrict__ f1mb,
    const float* __restrict__ f2mw, const float* __restrict__ f2mb,
    const float* __restrict__ f3mw, const float* __restrict__ f3mb,
    const float* __restrict__ f1vw, const float* __restrict__ f1vb,
    const float* __restrict__ f2vw, const float* __restrict__ f2vb,
    const float* __restrict__ f3vw, const float* __restrict__ f3vb,
    float* __restrict__ out) {
  bool vpath = (blockIdx.x == 1);
  const float* w1 = vpath ? f1vw : f1mw;
  const float* c1 = vpath ? f1vb : f1mb;
  const float* w2 = vpath ? f2vw : f2mw;
  const float* c2 = vpath ? f2vb : f2mb;
  __shared__ float gg[NB * 512];
  __shared__ float a1[NB * 256];
  __shared__ float a2[NB * 128];
  __shared__ float zz[NB * 128];
  __shared__ float nrm[NB];
  int t = threadIdx.x;
  for (int i = t; i < NB * 512; i += 256) gg[i] = g[i];
  __syncthreads();
  float o[NB];
  {
    #pragma unroll
    for (int b = 0; b < NB; ++b) o[b] = c1[t];
    const float* wr = w1 + (size_t)t * 512;
    for (int j = 0; j < 512; ++j) {
      float w = wr[j];
      #pragma unroll
      for (int b = 0; b < NB; ++b) o[b] += gg[b * 512 + j] * w;
    }
    float mean = 0.f;
    #pragma unroll
    for (int b = 0; b < NB; ++b) mean += o[b];
    mean *= (1.0f / NB);
    float var = 0.f;
    #pragma unroll
    for (int b = 0; b < NB; ++b) { float d = o[b] - mean; var += d * d; }
    var *= (1.0f / NB);
    float is = rsqrtf(var + 1e-5f);
    #pragma unroll
    for (int b = 0; b < NB; ++b) a1[b * 256 + t] = fmaxf((o[b] - mean) * is, 0.f);
  }
  __syncthreads();
  if (t < 128) {
    #pragma unroll
    for (int b = 0; b < NB; ++b) o[b] = c2[t];
    const float* wr = w2 + (size_t)t * 256;
    for (int j = 0; j < 256; ++j) {
      float w = wr[j];
      #pragma unroll
      for (int b = 0; b < NB; ++b) o[b] += a1[b * 256 + j] * w;
    }
    float mean = 0.f;
    #pragma unroll
    for (int b = 0; b < NB; ++b) mean += o[b];
    mean *= (1.0f / NB);
    float var = 0.f;
    #pragma unroll
    for (int b = 0; b < NB; ++b) { float d = o[b] - mean; var += d * d; }
    var *= (1.0f / NB);
    float is = rsqrtf(var + 1e-5f);
    #pragma unroll
    for (int b = 0; b < NB; ++b) a2[b * 128 + t] = fmaxf((o[b] - mean) * is, 0.f);
  }
  __syncthreads();
  if (!vpath) {
    if (t < 128) {
      const float* wr = f3mw + (size_t)t * 128;
      for (int b = 0; b < NB; ++b) {
        float s = f3mb[t];
        for (int j = 0; j < 128; ++j) s += a2[b * 128 + j] * wr[j];
        zz[b * 128 + t] = s;
      }
    }
    __syncthreads();
    if (t < NB) {
      float s = 0.f;
      for (int j = 0; j < 128; ++j) { float v = zz[t * 128 + j]; s += v * v; }
      nrm[t] = sqrtf(s);
    }
    __syncthreads();
    if (t < 128) {
      for (int b = 0; b < NB; ++b) out[b * 128 + t] = zz[b * 128 + t] / nrm[b];
    }
  } else {
    if (t < NB) {
      float s = f3vb[0];
      for (int j = 0; j < 128; ++j) s += a2[t * 128 + j] * f3vw[j];
      float sp = (s > 20.f) ? s : log1pf(expf(s));
      out[NB * 128 + t] = sp + 1.0f;
    }
  }
}

extern "C" void kernel_launch(void* const* d_in, const int* in_sizes, int n_in,
                              void* d_out, int out_size, void* d_ws, size_t ws_size,
                              hipStream_t stream) {
  const float* x  = (const float*)d_in[0];
  const float* w1 = (const float*)d_in[1];
  const float* b1 = (const float*)d_in[2];
  const float* w2 = (const float*)d_in[3];
  const float* b2 = (const float*)d_in[4];
  const float* w3 = (const float*)d_in[5];
  const float* b3 = (const float*)d_in[6];
  const float* w4 = (const float*)d_in[7];
  const float* b4 = (const float*)d_in[8];
  const float* a_wqk[4] = {(const float*)d_in[9],  (const float*)d_in[12], (const float*)d_in[15], (const float*)d_in[18]};
  const float* a_wt[4]  = {(const float*)d_in[10], (const float*)d_in[13], (const float*)d_in[16], (const float*)d_in[19]};
  const float* a_bt[4]  = {(const float*)d_in[11], (const float*)d_in[14], (const float*)d_in[17], (const float*)d_in[20]};
  int a_D[4] = {in_sizes[9], in_sizes[12], in_sizes[15], in_sizes[18]};
  const float* f1mw = (const float*)d_in[21]; const float* f1mb = (const float*)d_in[22];
  const float* f2mw = (const float*)d_in[23]; const float* f2mb = (const float*)d_in[24];
  const float* f3mw = (const float*)d_in[25]; const float* f3mb = (const float*)d_in[26];
  const float* f1vw = (const float*)d_in[27]; const float* f1vb = (const float*)d_in[28];
  const float* f2vw = (const float*)d_in[29]; const float* f2vb = (const float*)d_in[30];
  const float* f3vw = (const float*)d_in[31]; const float* f3vb = (const float*)d_in[32];
  float* out = (float*)d_out;

  float* ws = (float*)d_ws;
  float* xn     = ws; ws += (size_t)NB * NP * 3;
  float* dens   = ws; ws += NB * NP;
  float* maxinv = ws; ws += 16;
  float* Ls     = ws; ws += 16;
  float* rinv   = ws; ws += NB * NP;
  float* cinv   = ws; ws += NB * NP;
  float* g      = ws; ws += NB * 512;
  float* Hb     = ws; ws += (size_t)NB * 512 * NP;
  float* Ub     = ws; ws += (size_t)NB * 512 * NP;
  float* Tb     = ws; ws += (size_t)NB * 512 * NP;
  ushort* E     = (ushort*)Tb;   // E (64MB bf16) aliases Tb (dead when Tb is written)

  k_prep<<<NB * NP / 256, 256, 0, stream>>>(x, xn, Ub);   // Ub temporarily holds x^T [B,3,N]
  k_zero1<<<1, 64, 0, stream>>>(maxinv);
  k_density<<<NB * NP / 16, 512, 0, stream>>>(xn, dens, (int*)maxinv);

  auto conv = [&](const float* W, const float* bias, const float* IN, int Cin, int Cout, bool relu) {
    if (Cin < 64)
      k_gemm<<<dim3(NP / 64, Cout / 64, NB), 256, 0, stream>>>(W, IN, bias, Tb, Cin, Cout);
    else
      k_gemm_mfma<<<dim3(NP / 128, Cout / 128, NB), 256, 0, stream>>>(W, IN, bias, Tb, Cin, Cout);
    k_bn<<<Cout, 256, 0, stream>>>(Tb, Hb, Cout, relu ? 1 : 0, 0);
  };
  auto attn = [&](int li, int C) {
    k_attn_prep<<<1, 128, 0, stream>>>(a_wqk[li], a_D[li], maxinv, Ls);
    k_expmat<<<dim3(NB, NP / 4), 256, 0, stream>>>(dens, Ls, E, rinv);
    k_csum<<<dim3(NB, NP / 4), 256, 0, stream>>>(E, rinv, cinv);
    k_xr_mfma<<<dim3(NP / 128, C / 128, NB), 256, 0, stream>>>(Hb, Ub, E, rinv, cinv, C);
    k_gemm_mfma<<<dim3(NP / 128, C / 128, NB), 256, 0, stream>>>(a_wt[li], Ub, a_bt[li], Tb, C, C);
    k_bn<<<C, 256, 0, stream>>>(Tb, Hb, C, 1, 1);
  };

  conv(w1, b1, Ub, 3, 128, true);
  attn(0, 128);
  conv(w2, b2, Hb, 128, 128, true);
  attn(1, 128);
  conv(w3, b3, Hb, 128, 256, true);
  attn(2, 256);
  conv(w4, b4, Hb, 256, 512, false);
  attn(3, 512);

  k_maxpool<<<NB * 512, 64, 0, stream>>>(Hb, g);
  k_head<<<2, 256, 0, stream>>>(g, f1mw, f1mb, f2mw, f2mb, f3mw, f3mb,
                                f1vw, f1vb, f2vw, f2vb, f3vw, f3vb, out);
}

// Round 8
// 476.475 us; speedup vs baseline: 2.5610x; 1.8544x over previous
//
#include <hip/hip_runtime.h>
#include <cfloat>
#include <cmath>

constexpr int NB = 8;
constexpr int NP = 2048;
constexpr int NK = 11;   // Taylor terms k=0..10; err <= s^11/11! (s ~ 0.3) ~ 1e-11

typedef __attribute__((ext_vector_type(4))) float f32x4;
typedef __attribute__((ext_vector_type(8))) short bf16x8;
#define MFMA16(a, b, c) __builtin_amdgcn_mfma_f32_16x16x32_bf16(a, b, c, 0, 0, 0)

__device__ inline ushort f2bf(float f) {   // round-to-nearest-even f32 -> bf16
  union { float f; unsigned u; } v; v.f = f;
  unsigned r = v.u + 0x7FFFu + ((v.u >> 16) & 1u);
  return (ushort)(r >> 16);
}
__device__ inline unsigned pk2bf(float a, float b) {
  return (unsigned)f2bf(a) | ((unsigned)f2bf(b) << 16);
}

// Per-32-lane-half sum: after row_shr 1/2/4/8 + row_bcast:15, lane31 holds
// sum(lanes 0..31), lane63 holds sum(lanes 32..63).
__device__ inline int dpp_half_sum_i32(int c) {
  c += __builtin_amdgcn_update_dpp(0, c, 0x111, 0xf, 0xf, true);  // row_shr:1
  c += __builtin_amdgcn_update_dpp(0, c, 0x112, 0xf, 0xf, true);  // row_shr:2
  c += __builtin_amdgcn_update_dpp(0, c, 0x114, 0xf, 0xf, true);  // row_shr:4
  c += __builtin_amdgcn_update_dpp(0, c, 0x118, 0xf, 0xf, true);  // row_shr:8
  c += __builtin_amdgcn_update_dpp(0, c, 0x142, 0xf, 0xf, true);  // row_bcast:15
  return c;
}

// ---------- prep: normalize x -> xn ; transpose x -> xt [B,3,N] ----------
__global__ void k_prep(const float* __restrict__ x, float* __restrict__ xn, float* __restrict__ xt) {
  int i = blockIdx.x * blockDim.x + threadIdx.x;
  if (i >= NB * NP) return;
  int b = i >> 11, n = i & (NP - 1);
  float a0 = x[i * 3 + 0], a1 = x[i * 3 + 1], a2 = x[i * 3 + 2];
  float rn = rsqrtf(a0 * a0 + a1 * a1 + a2 * a2);
  xn[i * 3 + 0] = a0 * rn; xn[i * 3 + 1] = a1 * rn; xn[i * 3 + 2] = a2 * rn;
  float* xb = xt + (size_t)b * 3 * NP;
  xb[0 * NP + n] = a0; xb[1 * NP + n] = a1; xb[2 * NP + n] = a2;
}

__global__ void k_zero1(float* p) { if (threadIdx.x == 0) p[0] = 0.f; }

// ---------- density: 2 rows per wave, branchless binary search ----------
__global__ __launch_bounds__(512) void k_density(const float* __restrict__ xn,
                                                 float* __restrict__ inv,
                                                 int* __restrict__ maxinv) {
  __shared__ float sx[NP], sy[NP], sz[NP];
  int t = threadIdx.x;
  int w = t >> 6, lane = t & 63, half = lane >> 5, sl = lane & 31;
  int row0 = blockIdx.x * 16;
  int b = row0 >> 11;
  const float4* xb4 = (const float4*)(xn + (size_t)b * NP * 3);
  {
    float4 a = xb4[t * 3 + 0], c4 = xb4[t * 3 + 1], e4 = xb4[t * 3 + 2];
    int p = t * 4;
    sx[p + 0] = a.x;  sy[p + 0] = a.y;  sz[p + 0] = a.z;
    sx[p + 1] = a.w;  sy[p + 1] = c4.x; sz[p + 1] = c4.y;
    sx[p + 2] = c4.z; sy[p + 2] = c4.w; sz[p + 2] = e4.x;
    sx[p + 3] = e4.y; sy[p + 3] = e4.z; sz[p + 3] = e4.w;
  }
  __syncthreads();
  int row = row0 + w * 2 + half;
  int n = row & (NP - 1);
  float px = sx[n], py = sy[n], pz = sz[n];
  float d[64];
  float mn = FLT_MAX, mx = -FLT_MAX;
  #pragma unroll
  for (int k = 0; k < 64; ++k) {
    int m = sl + (k << 5);
    float v = 1.0f - (px * sx[m] + py * sy[m] + pz * sz[m]);
    d[k] = v;
    mn = fminf(mn, v); mx = fmaxf(mx, v);
  }
  #pragma unroll
  for (int off = 16; off; off >>= 1) {
    mn = fminf(mn, __shfl_xor(mn, off));
    mx = fminf(mx, __shfl_xor(mx, off));
  }
  float lo = mn, hi = mx + 1e-6f;
  int baddr = (half ? 63 : 31) << 2;
  for (int it = 0; it < 18; ++it) {
    float tt = 0.5f * (lo + hi);
    int c = 0;
    #pragma unroll
    for (int k = 0; k < 64; ++k) c += (d[k] < tt) ? 1 : 0;
    c = dpp_half_sum_i32(c);
    int ct = __builtin_amdgcn_ds_bpermute(baddr, c);
    bool le = ct <= 32;
    lo = le ? tt : lo;
    hi = le ? hi : tt;
  }
  float s = 0.f; int c = 0;
  #pragma unroll
  for (int k = 0; k < 64; ++k) {
    bool p = d[k] < lo;
    s += p ? d[k] : 0.f;
    c += p ? 1 : 0;
  }
  c = dpp_half_sum_i32(c);
  int ctot = __builtin_amdgcn_ds_bpermute(baddr, c);
  #pragma unroll
  for (int off = 16; off; off >>= 1) s += __shfl_xor(s, off);
  float sum = s + (float)(32 - ctot) * lo;
  if (sl == 0) {
    float iv = 32.0f / sum;
    inv[row] = iv;
    atomicMax(maxinv, __float_as_int(iv));
  }
}

__global__ void k_scale(float* __restrict__ dens, const float* __restrict__ maxinv) {
  int i = blockIdx.x * 256 + threadIdx.x;
  if (i < NB * NP) dens[i] *= (1.0f / maxinv[0]);
}

// ---------- coef[k] = s^k / k!,  s = sum(wqk^2) ----------
__global__ __launch_bounds__(64) void k_coef(const float* __restrict__ wqk, int D,
                                             float* __restrict__ coef) {
  int lane = threadIdx.x;
  float v = 0.f;
  for (int i = lane; i < D; i += 64) v += wqk[i] * wqk[i];
  #pragma unroll
  for (int off = 32; off; off >>= 1) v += __shfl_xor(v, off);
  if (lane == 0) {
    float c = 1.f;
    coef[0] = 1.f;
    for (int k = 1; k < NK; ++k) { c *= v / (float)k; coef[k] = c; }
  }
}

// ---------- per-batch: S_k -> rinv -> T_k -> cinv (all in one block) ----------
__global__ __launch_bounds__(256) void k_attn_small(const float* __restrict__ dens,
                                                    const float* __restrict__ coef,
                                                    float* __restrict__ rinv,
                                                    float* __restrict__ cinv) {
  int b = blockIdx.x, t = threadIdx.x, w = t >> 6, lane = t & 63;
  const float* db = dens + b * NP;
  float d[8], r[8];
  *(float4*)&d[0] = *(const float4*)(db + t * 8);
  *(float4*)&d[4] = *(const float4*)(db + t * 8 + 4);
  __shared__ float part[NK][4];
  float q[NK];
  // S_k = sum d^k
  {
    float acc[NK];
    #pragma unroll
    for (int k = 0; k < NK; ++k) acc[k] = 0.f;
    #pragma unroll
    for (int e = 0; e < 8; ++e) {
      float p = 1.f;
      #pragma unroll
      for (int k = 0; k < NK; ++k) { acc[k] += p; p *= d[e]; }
    }
    #pragma unroll
    for (int k = 0; k < NK; ++k) {
      float a = acc[k];
      #pragma unroll
      for (int off = 32; off; off >>= 1) a += __shfl_xor(a, off);
      if (lane == 0) part[k][w] = a;
    }
    __syncthreads();
    #pragma unroll
    for (int k = 0; k < NK; ++k)
      q[k] = coef[k] * ((part[k][0] + part[k][1]) + (part[k][2] + part[k][3]));
    __syncthreads();
  }
  // rinv[n] = 1 / sum_k q_k d^k
  #pragma unroll
  for (int e = 0; e < 8; ++e) {
    float poly = q[NK - 1];
    #pragma unroll
    for (int k = NK - 2; k >= 0; --k) poly = poly * d[e] + q[k];
    r[e] = 1.0f / poly;
  }
  *(float4*)(rinv + b * NP + t * 8)     = *(float4*)&r[0];
  *(float4*)(rinv + b * NP + t * 8 + 4) = *(float4*)&r[4];
  // T_k = sum rinv d^k
  {
    float acc[NK];
    #pragma unroll
    for (int k = 0; k < NK; ++k) acc[k] = 0.f;
    #pragma unroll
    for (int e = 0; e < 8; ++e) {
      float p = r[e];
      #pragma unroll
      for (int k = 0; k < NK; ++k) { acc[k] += p; p *= d[e]; }
    }
    #pragma unroll
    for (int k = 0; k < NK; ++k) {
      float a = acc[k];
      #pragma unroll
      for (int off = 32; off; off >>= 1) a += __shfl_xor(a, off);
      if (lane == 0) part[k][w] = a;
    }
    __syncthreads();
    #pragma unroll
    for (int k = 0; k < NK; ++k)
      q[k] = coef[k] * ((part[k][0] + part[k][1]) + (part[k][2] + part[k][3]));
  }
  // cinv[m] = 1 / (1e-9 + sum_k q_k d^k)
  #pragma unroll
  for (int e = 0; e < 8; ++e) {
    float poly = q[NK - 1];
    #pragma unroll
    for (int k = NK - 2; k >= 0; --k) poly = poly * d[e] + q[k];
    r[e] = 1.0f / (poly + 1e-9f);
  }
  *(float4*)(cinv + b * NP + t * 8)     = *(float4*)&r[0];
  *(float4*)(cinv + b * NP + t * 8 + 4) = *(float4*)&r[4];
}

// ---------- fused x_r: one block per (b,c) row ----------
// P_k = sum_n H[c][n] rinv[n] d^k ; U[c][m] = H[c][m] - cinv[m]*sum_k coef_k P_k d^k
__global__ __launch_bounds__(256) void k_xrP(const float* __restrict__ H, float* __restrict__ U,
                                             const float* __restrict__ dens,
                                             const float* __restrict__ rinv,
                                             const float* __restrict__ cinv,
                                             const float* __restrict__ coef, int C) {
  int b = blockIdx.y, c = blockIdx.x, t = threadIdx.x, w = t >> 6, lane = t & 63;
  const float* Hc = H + ((size_t)b * C + c) * NP;
  float* Uc = U + ((size_t)b * C + c) * NP;
  const float* db = dens + b * NP;
  const float* rb = rinv + b * NP;
  const float* cb = cinv + b * NP;
  float h[8], d[8], r[8], cv[8];
  *(float4*)&h[0] = *(const float4*)(Hc + t * 8);
  *(float4*)&h[4] = *(const float4*)(Hc + t * 8 + 4);
  *(float4*)&d[0] = *(const float4*)(db + t * 8);
  *(float4*)&d[4] = *(const float4*)(db + t * 8 + 4);
  *(float4*)&r[0] = *(const float4*)(rb + t * 8);
  *(float4*)&r[4] = *(const float4*)(rb + t * 8 + 4);
  *(float4*)&cv[0] = *(const float4*)(cb + t * 8);
  *(float4*)&cv[4] = *(const float4*)(cb + t * 8 + 4);
  float acc[NK];
  #pragma unroll
  for (int k = 0; k < NK; ++k) acc[k] = 0.f;
  #pragma unroll
  for (int e = 0; e < 8; ++e) {
    float p = h[e] * r[e];
    #pragma unroll
    for (int k = 0; k < NK; ++k) { acc[k] += p; p *= d[e]; }
  }
  __shared__ float part[NK][4];
  #pragma unroll
  for (int k = 0; k < NK; ++k) {
    float a = acc[k];
    #pragma unroll
    for (int off = 32; off; off >>= 1) a += __shfl_xor(a, off);
    if (lane == 0) part[k][w] = a;
  }
  __syncthreads();
  float q[NK];
  #pragma unroll
  for (int k = 0; k < NK; ++k)
    q[k] = coef[k] * ((part[k][0] + part[k][1]) + (part[k][2] + part[k][3]));
  float u[8];
  #pragma unroll
  for (int e = 0; e < 8; ++e) {
    float poly = q[NK - 1];
    #pragma unroll
    for (int k = NK - 2; k >= 0; --k) poly = poly * d[e] + q[k];
    u[e] = h[e] - cv[e] * poly;
  }
  *(float4*)(Uc + t * 8)     = *(float4*)&u[0];
  *(float4*)(Uc + t * 8 + 4) = *(float4*)&u[4];
}

// ---------- conv1x1 via bf16 MFMA ----------
constexpr int LDA = 72;  // bf16 units per LDS row (64 + 8 pad)

__global__ __launch_bounds__(256) void k_gemm_mfma(const float* __restrict__ W,
                                                   const float* __restrict__ IN,
                                                   const float* __restrict__ bias,
                                                   float* __restrict__ OUT,
                                                   int Cin, int Cout) {
  int b = blockIdx.z, n0 = blockIdx.x * 128, o0 = blockIdx.y * 128;
  int tid = threadIdx.x, lane = tid & 63, w = tid >> 6;
  int wr = w >> 1, wc = w & 1;
  const float* Ib = IN + (size_t)b * Cin * NP;
  float* Ob = OUT + (size_t)b * Cout * NP;
  __shared__ ushort Asm[128 * LDA];
  __shared__ ushort Bsm[128 * LDA];
  f32x4 acc[4][4];
  #pragma unroll
  for (int i = 0; i < 4; ++i)
    #pragma unroll
    for (int j = 0; j < 4; ++j) acc[i][j] = (f32x4)(0.0f);

  int row = tid >> 1, half = tid & 1;
  int csub = tid & 63, q = tid >> 6;
  for (int cc0 = 0; cc0 < Cin; cc0 += 64) {
    __syncthreads();
    {   // A: rows=o (128), cols=c' (64) from W
      const float* src = W + (size_t)(o0 + row) * Cin + cc0 + half * 32;
      unsigned* dst = (unsigned*)(Asm + row * LDA + half * 32);
      #pragma unroll
      for (int i = 0; i < 8; ++i) {
        float4 v = *(const float4*)(src + i * 4);
        dst[i * 2 + 0] = pk2bf(v.x, v.y);
        dst[i * 2 + 1] = pk2bf(v.z, v.w);
      }
      // B: rows=n' (128), cols=c' (64) — transpose of IN[c][n]
      const float* isrc = Ib + (size_t)(cc0 + csub) * NP + n0 + q * 32;
      #pragma unroll
      for (int i = 0; i < 8; ++i) {
        float4 v = *(const float4*)(isrc + i * 4);
        ushort* bd = Bsm + (q * 32 + i * 4) * LDA + csub;
        bd[0]       = f2bf(v.x);
        bd[LDA]     = f2bf(v.y);
        bd[2 * LDA] = f2bf(v.z);
        bd[3 * LDA] = f2bf(v.w);
      }
    }
    __syncthreads();
    #pragma unroll
    for (int kk = 0; kk < 64; kk += 32) {
      bf16x8 af[4], bfr[4];
      #pragma unroll
      for (int i = 0; i < 4; ++i) {
        af[i]  = *(const bf16x8*)(Asm + (wr * 64 + i * 16 + (lane & 15)) * LDA + kk + (lane >> 4) * 8);
        bfr[i] = *(const bf16x8*)(Bsm + (wc * 64 + i * 16 + (lane & 15)) * LDA + kk + (lane >> 4) * 8);
      }
      #pragma unroll
      for (int i = 0; i < 4; ++i)
        #pragma unroll
        for (int j = 0; j < 4; ++j)
          acc[i][j] = MFMA16(af[i], bfr[j], acc[i][j]);
    }
  }
  #pragma unroll
  for (int i = 0; i < 4; ++i) {
    #pragma unroll
    for (int r = 0; r < 4; ++r) {
      int o = o0 + wr * 64 + i * 16 + (lane >> 4) * 4 + r;
      float bv = bias[o];
      #pragma unroll
      for (int j = 0; j < 4; ++j) {
        int n = n0 + wc * 64 + j * 16 + (lane & 15);
        Ob[(size_t)o * NP + n] = acc[i][j][r] + bv;
      }
    }
  }
}

// ---------- fp32 GEMM (conv1 only, Cin=3) ----------
__global__ __launch_bounds__(256) void k_gemm(const float* __restrict__ W,
                                              const float* __restrict__ IN,
                                              const float* __restrict__ bias,
                                              float* __restrict__ OUT,
                                              int Cin, int Cout) {
  int b = blockIdx.z;
  int n0 = blockIdx.x * 64;
  int o0 = blockIdx.y * 64;
  int tid = threadIdx.x;
  int tx = tid & 15, ty = tid >> 4;
  const float* Ib = IN + (size_t)b * Cin * NP;
  float* Ob = OUT + (size_t)b * Cout * NP;
  __shared__ float Wt[64][65];
  __shared__ float It[64][65];
  float acc[4][4] = {};
  for (int c0 = 0; c0 < Cin; c0 += 64) {
    __syncthreads();
    {
      int ci = tid & 63, ob4 = tid >> 6;
      bool cv = (c0 + ci) < Cin;
      #pragma unroll
      for (int k = 0; k < 16; ++k) {
        int oi = ob4 + (k << 2);
        Wt[ci][oi] = cv ? W[(size_t)(o0 + oi) * Cin + c0 + ci] : 0.f;
      }
      int ni = tid & 63, cb4 = tid >> 6;
      #pragma unroll
      for (int k = 0; k < 16; ++k) {
        int ci2 = cb4 + (k << 2);
        It[ci2][ni] = (c0 + ci2) < Cin ? Ib[(size_t)(c0 + ci2) * NP + n0 + ni] : 0.f;
      }
    }
    __syncthreads();
    #pragma unroll 4
    for (int ci = 0; ci < 64; ++ci) {
      float a0 = Wt[ci][ty * 4 + 0], a1 = Wt[ci][ty * 4 + 1], a2 = Wt[ci][ty * 4 + 2], a3 = Wt[ci][ty * 4 + 3];
      float b0 = It[ci][tx * 4 + 0], b1 = It[ci][tx * 4 + 1], b2 = It[ci][tx * 4 + 2], b3 = It[ci][tx * 4 + 3];
      acc[0][0] += a0 * b0; acc[0][1] += a0 * b1; acc[0][2] += a0 * b2; acc[0][3] += a0 * b3;
      acc[1][0] += a1 * b0; acc[1][1] += a1 * b1; acc[1][2] += a1 * b2; acc[1][3] += a1 * b3;
      acc[2][0] += a2 * b0; acc[2][1] += a2 * b1; acc[2][2] += a2 * b2; acc[2][3] += a2 * b3;
      acc[3][0] += a3 * b0; acc[3][1] += a3 * b1; acc[3][2] += a3 * b2; acc[3][3] += a3 * b3;
    }
  }
  #pragma unroll
  for (int i = 0; i < 4; ++i) {
    int o = o0 + ty * 4 + i;
    float bv = bias[o];
    #pragma unroll
    for (int j = 0; j < 4; ++j) {
      int n = n0 + tx * 4 + j;
      Ob[(size_t)o * NP + n] = acc[i][j] + bv;
    }
  }
}

// ---------- fused BN: stats + apply, values held in registers ----------
__global__ __launch_bounds__(256) void k_bn(const float* __restrict__ T, float* __restrict__ H,
                                            int C, int relu, int acc) {
  int c = blockIdx.x, t = threadIdx.x, w = t >> 6, lane = t & 63;
  float4 v[16];
  float s = 0.f, s2 = 0.f;
  #pragma unroll
  for (int b = 0; b < NB; ++b) {
    const float4* p = (const float4*)(T + ((size_t)b * C + c) * NP);
    #pragma unroll
    for (int i = 0; i < 2; ++i) {
      float4 x = p[t + i * 256];
      v[b * 2 + i] = x;
      s += (x.x + x.y) + (x.z + x.w);
      s2 += (x.x * x.x + x.y * x.y) + (x.z * x.z + x.w * x.w);
    }
  }
  #pragma unroll
  for (int off = 32; off; off >>= 1) { s += __shfl_xor(s, off); s2 += __shfl_xor(s2, off); }
  __shared__ float ps[4], ps2[4];
  if (lane == 0) { ps[w] = s; ps2[w] = s2; }
  __syncthreads();
  float ts = (ps[0] + ps[1]) + (ps[2] + ps[3]);
  float ts2 = (ps2[0] + ps2[1]) + (ps2[2] + ps2[3]);
  float m = ts * (1.0f / (NB * NP));
  float var = ts2 * (1.0f / (NB * NP)) - m * m;
  float is = rsqrtf(var + 1e-5f);
  #pragma unroll
  for (int b = 0; b < NB; ++b) {
    float4* hp = (float4*)(H + ((size_t)b * C + c) * NP);
    #pragma unroll
    for (int i = 0; i < 2; ++i) {
      float4 x = v[b * 2 + i];
      x.x = (x.x - m) * is; x.y = (x.y - m) * is; x.z = (x.z - m) * is; x.w = (x.w - m) * is;
      if (relu) {
        x.x = fmaxf(x.x, 0.f); x.y = fmaxf(x.y, 0.f); x.z = fmaxf(x.z, 0.f); x.w = fmaxf(x.w, 0.f);
      }
      if (acc) {
        float4 h = hp[t + i * 256];
        x.x += h.x; x.y += h.y; x.z += h.z; x.w += h.w;
      }
      hp[t + i * 256] = x;
    }
  }
}

// ---------- global max pool over N ----------
__global__ __launch_bounds__(64) void k_maxpool(const float* __restrict__ H, float* __restrict__ g) {
  int bf = blockIdx.x;
  const float* p = H + (size_t)bf * NP;
  int lane = threadIdx.x;
  float mx = -FLT_MAX;
  for (int n = lane; n < NP; n += 64) mx = fmaxf(mx, p[n]);
  #pragma unroll
  for (int off = 32; off > 0; off >>= 1) mx = fmaxf(mx, __shfl_xor(mx, off));
  if (lane == 0) g[bf] = mx;
}

// ---------- MLP head ----------
__global__ __launch_bounds__(256) void k_head(const float* __restrict__ g,
    const float* __restrict__ f1mw, const float* __restrict__ f1mb,
    const float* __restrict__ f2mw, const float* __restrict__ f2mb,
    const float* __restrict__ f3mw, const float* __restrict__ f3mb,
    const float* __restrict__ f1vw, const float* __restrict__ f1vb,
    const float* __restrict__ f2vw, const float* __restrict__ f2vb,
    const float* __restrict__ f3vw, const float* __restrict__ f3vb,
    float* __restrict__ out) {
  bool vpath = (blockIdx.x == 1);
  const float* w1 = vpath ? f1vw : f1mw;
  const float* c1 = vpath ? f1vb : f1mb;
  const float* w2 = vpath ? f2vw : f2mw;
  const float* c2 = vpath ? f2vb : f2mb;
  __shared__ float gg[NB * 512];
  __shared__ float a1[NB * 256];
  __shared__ float a2[NB * 128];
  __shared__ float zz[NB * 128];
  __shared__ float nrm[NB];
  int t = threadIdx.x;
  for (int i = t; i < NB * 512; i += 256) gg[i] = g[i];
  __syncthreads();
  float o[NB];
  {
    #pragma unroll
    for (int b = 0; b < NB; ++b) o[b] = c1[t];
    const float* wr = w1 + (size_t)t * 512;
    for (int j = 0; j < 512; ++j) {
      float w = wr[j];
      #pragma unroll
      for (int b = 0; b < NB; ++b) o[b] += gg[b * 512 + j] * w;
    }
    float mean = 0.f;
    #pragma unroll
    for (int b = 0; b < NB; ++b) mean += o[b];
    mean *= (1.0f / NB);
    float var = 0.f;
    #pragma unroll
    for (int b = 0; b < NB; ++b) { float d = o[b] - mean; var += d * d; }
    var *= (1.0f / NB);
    float is = rsqrtf(var + 1e-5f);
    #pragma unroll
    for (int b = 0; b < NB; ++b) a1[b * 256 + t] = fmaxf((o[b] - mean) * is, 0.f);
  }
  __syncthreads();
  if (t < 128) {
    #pragma unroll
    for (int b = 0; b < NB; ++b) o[b] = c2[t];
    const float* wr = w2 + (size_t)t * 256;
    for (int j = 0; j < 256; ++j) {
      float w = wr[j];
      #pragma unroll
      for (int b = 0; b < NB; ++b) o[b] += a1[b * 256 + j] * w;
    }
    float mean = 0.f;
    #pragma unroll
    for (int b = 0; b < NB; ++b) mean += o[b];
    mean *= (1.0f / NB);
    float var = 0.f;
    #pragma unroll
    for (int b = 0; b < NB; ++b) { float d = o[b] - mean; var += d * d; }
    var *= (1.0f / NB);
    float is = rsqrtf(var + 1e-5f);
    #pragma unroll
    for (int b = 0; b < NB; ++b) a2[b * 128 + t] = fmaxf((o[b] - mean) * is, 0.f);
  }
  __syncthreads();
  if (!vpath) {
    if (t < 128) {
      const float* wr = f3mw + (size_t)t * 128;
      for (int b = 0; b < NB; ++b) {
        float s = f3mb[t];
        for (int j = 0; j < 128; ++j) s += a2[b * 128 + j] * wr[j];
        zz[b * 128 + t] = s;
      }
    }
    __syncthreads();
    if (t < NB) {
      float s = 0.f;
      for (int j = 0; j < 128; ++j) { float v = zz[t * 128 + j]; s += v * v; }
      nrm[t] = sqrtf(s);
    }
    __syncthreads();
    if (t < 128) {
      for (int b = 0; b < NB; ++b) out[b * 128 + t] = zz[b * 128 + t] / nrm[b];
    }
  } else {
    if (t < NB) {
      float s = f3vb[0];
      for (int j = 0; j < 128; ++j) s += a2[t * 128 + j] * f3vw[j];
      float sp = (s > 20.f) ? s : log1pf(expf(s));
      out[NB * 128 + t] = sp + 1.0f;
    }
  }
}

extern "C" void kernel_launch(void* const* d_in, const int* in_sizes, int n_in,
                              void* d_out, int out_size, void* d_ws, size_t ws_size,
                              hipStream_t stream) {
  const float* x  = (const float*)d_in[0];
  const float* w1 = (const float*)d_in[1];
  const float* b1 = (const float*)d_in[2];
  const float* w2 = (const float*)d_in[3];
  const float* b2 = (const float*)d_in[4];
  const float* w3 = (const float*)d_in[5];
  const float* b3 = (const float*)d_in[6];
  const float* w4 = (const float*)d_in[7];
  const float* b4 = (const float*)d_in[8];
  const float* a_wqk[4] = {(const float*)d_in[9],  (const float*)d_in[12], (const float*)d_in[15], (const float*)d_in[18]};
  const float* a_wt[4]  = {(const float*)d_in[10], (const float*)d_in[13], (const float*)d_in[16], (const float*)d_in[19]};
  const float* a_bt[4]  = {(const float*)d_in[11], (const float*)d_in[14], (const float*)d_in[17], (const float*)d_in[20]};
  int a_D[4] = {in_sizes[9], in_sizes[12], in_sizes[15], in_sizes[18]};
  const float* f1mw = (const float*)d_in[21]; const float* f1mb = (const float*)d_in[22];
  const float* f2mw = (const float*)d_in[23]; const float* f2mb = (const float*)d_in[24];
  const float* f3mw = (const float*)d_in[25]; const float* f3mb = (const float*)d_in[26];
  const float* f1vw = (const float*)d_in[27]; const float* f1vb = (const float*)d_in[28];
  const float* f2vw = (const float*)d_in[29]; const float* f2vb = (const float*)d_in[30];
  const float* f3vw = (const float*)d_in[31]; const float* f3vb = (const float*)d_in[32];
  float* out = (float*)d_out;

  float* ws = (float*)d_ws;
  float* xn     = ws; ws += (size_t)NB * NP * 3;
  float* dens   = ws; ws += NB * NP;
  float* maxinv = ws; ws += 16;
  float* coef   = ws; ws += 16;
  float* rinv   = ws; ws += NB * NP;
  float* cinv   = ws; ws += NB * NP;
  float* g      = ws; ws += NB * 512;
  float* Hb     = ws; ws += (size_t)NB * 512 * NP;
  float* Ub     = ws; ws += (size_t)NB * 512 * NP;
  float* Tb     = ws; ws += (size_t)NB * 512 * NP;

  k_prep<<<NB * NP / 256, 256, 0, stream>>>(x, xn, Ub);   // Ub temporarily holds x^T [B,3,N]
  k_zero1<<<1, 64, 0, stream>>>(maxinv);
  k_density<<<NB * NP / 16, 512, 0, stream>>>(xn, dens, (int*)maxinv);
  k_scale<<<NB * NP / 256, 256, 0, stream>>>(dens, maxinv);

  auto conv = [&](const float* W, const float* bias, const float* IN, int Cin, int Cout, bool relu) {
    if (Cin < 64)
      k_gemm<<<dim3(NP / 64, Cout / 64, NB), 256, 0, stream>>>(W, IN, bias, Tb, Cin, Cout);
    else
      k_gemm_mfma<<<dim3(NP / 128, Cout / 128, NB), 256, 0, stream>>>(W, IN, bias, Tb, Cin, Cout);
    k_bn<<<Cout, 256, 0, stream>>>(Tb, Hb, Cout, relu ? 1 : 0, 0);
  };
  auto attn = [&](int li, int C) {
    k_coef<<<1, 64, 0, stream>>>(a_wqk[li], a_D[li], coef);
    k_attn_small<<<NB, 256, 0, stream>>>(dens, coef, rinv, cinv);
    k_xrP<<<dim3(C, NB), 256, 0, stream>>>(Hb, Ub, dens, rinv, cinv, coef, C);
    k_gemm_mfma<<<dim3(NP / 128, C / 128, NB), 256, 0, stream>>>(a_wt[li], Ub, a_bt[li], Tb, C, C);
    k_bn<<<C, 256, 0, stream>>>(Tb, Hb, C, 1, 1);
  };

  conv(w1, b1, Ub, 3, 128, true);
  attn(0, 128);
  conv(w2, b2, Hb, 128, 128, true);
  attn(1, 128);
  conv(w3, b3, Hb, 128, 256, true);
  attn(2, 256);
  conv(w4, b4, Hb, 256, 512, false);
  attn(3, 512);

  k_maxpool<<<NB * 512, 64, 0, stream>>>(Hb, g);
  k_head<<<2, 256, 0, stream>>>(g, f1mw, f1mb, f2mw, f2mb, f3mw, f3mb,
                                f1vw, f1vb, f2vw, f2vb, f3vw, f3vb, out);
}